// Round 1
// baseline (609.147 us; speedup 1.0000x reference)
//
#include <hip/hip_runtime.h>
#include <hip/hip_bf16.h>

typedef __attribute__((ext_vector_type(4))) float f32x4;
typedef __attribute__((ext_vector_type(8))) __bf16 bf16x8;
typedef __attribute__((ext_vector_type(4))) __bf16 bf16x4;

static constexpr int E    = 1024;
static constexpr int TOK  = 8192;   // 8 * 1024 tokens
static constexpr int HID  = 4096;

#define DEVINL __device__ __forceinline__

// async global->LDS, 16B per lane. LDS dest must be lane-linear (wave base + lane*16).
DEVINL void gload16(const void* g, void* l) {
  __builtin_amdgcn_global_load_lds((__attribute__((address_space(1))) void*)g,
                                   (__attribute__((address_space(3))) void*)l, 16, 0, 0);
}

// ---------------------------------------------------------------------------
// Weight convert + transpose: W[K][N] f32 -> Wt[N][K] bf16 (32x32 LDS tiles)
// ---------------------------------------------------------------------------
__global__ __launch_bounds__(256) void wconv_kernel(const float* __restrict__ W,
                                                    __bf16* __restrict__ Wt,
                                                    int K, int N) {
  __shared__ float tile[32][33];
  const int t  = threadIdx.x;
  const long k0 = (long)blockIdx.y * 32;
  const long n0 = (long)blockIdx.x * 32;
  const int r  = t >> 3;
  const int c4 = (t & 7) * 4;
  float4 v = *(const float4*)&W[(k0 + r) * N + n0 + c4];
  tile[r][c4 + 0] = v.x; tile[r][c4 + 1] = v.y;
  tile[r][c4 + 2] = v.z; tile[r][c4 + 3] = v.w;
  __syncthreads();
  bf16x4 o;
#pragma unroll
  for (int i = 0; i < 4; ++i) o[i] = (__bf16)tile[c4 + i][r];
  *(bf16x4*)&Wt[(n0 + r) * K + k0 + c4] = o;
}

// ---------------------------------------------------------------------------
// LayerNorm (fp32 in) -> bf16 out. One block per row of 1024.
// ---------------------------------------------------------------------------
__global__ __launch_bounds__(256) void ln_kernel(const float* __restrict__ X,
                                                 const float* __restrict__ g,
                                                 const float* __restrict__ be,
                                                 __bf16* __restrict__ O) {
  const int t = threadIdx.x;
  const long row = blockIdx.x;
  float4 v = *(const float4*)&X[row * E + t * 4];
  float s  = v.x + v.y + v.z + v.w;
  float ss = v.x * v.x + v.y * v.y + v.z * v.z + v.w * v.w;
#pragma unroll
  for (int off = 32; off; off >>= 1) {
    s  += __shfl_down(s, off);
    ss += __shfl_down(ss, off);
  }
  __shared__ float red[8];
  const int w = t >> 6;
  if ((t & 63) == 0) { red[w] = s; red[4 + w] = ss; }
  __syncthreads();
  s  = red[0] + red[1] + red[2] + red[3];
  ss = red[4] + red[5] + red[6] + red[7];
  const float mean = s * (1.0f / E);
  const float var  = ss * (1.0f / E) - mean * mean;
  const float rstd = rsqrtf(var + 1e-5f);
  float4 gv = *(const float4*)&g[t * 4];
  float4 bv = *(const float4*)&be[t * 4];
  bf16x4 o;
  o[0] = (__bf16)((v.x - mean) * rstd * gv.x + bv.x);
  o[1] = (__bf16)((v.y - mean) * rstd * gv.y + bv.y);
  o[2] = (__bf16)((v.z - mean) * rstd * gv.z + bv.z);
  o[3] = (__bf16)((v.w - mean) * rstd * gv.w + bv.w);
  *(bf16x4*)&O[row * E + t * 4] = o;
}

// ---------------------------------------------------------------------------
// GEMM: C[M][N] = op(A[M][K] @ Bt[N][K]^T + bias) (+resid). bf16 MFMA 16x16x32.
// 128x128 block tile, BK=32, 4 waves (2x2), 64x64 per wave.
// ---------------------------------------------------------------------------
template <bool RELU, bool RESID, bool OUTBF>
__global__ __launch_bounds__(256) void gemm_kernel(const __bf16* __restrict__ A,
                                                   const __bf16* __restrict__ Bt,
                                                   const float* __restrict__ bias,
                                                   const float* resid,
                                                   void* Cout,
                                                   int M, int N, int K,
                                                   float out_scale) {
  __shared__ __align__(16) __bf16 As[128 * 32];  // [row][k] 64B rows
  __shared__ __align__(16) __bf16 Bs[128 * 32];  // [col][k]
  const int t    = threadIdx.x;
  const int lane = t & 63;
  const int wv   = t >> 6;
  const int wr   = wv >> 1;   // 0..1
  const int wc   = wv & 1;    // 0..1
  const long brow = (long)blockIdx.y * 128;
  const long bcol = (long)blockIdx.x * 128;

  f32x4 acc[4][4];
  const f32x4 z4 = {0.f, 0.f, 0.f, 0.f};
#pragma unroll
  for (int i = 0; i < 4; ++i)
#pragma unroll
    for (int n = 0; n < 4; ++n) acc[i][n] = z4;

  const __bf16* Ab = A  + brow * K;
  const __bf16* Bb = Bt + bcol * K;

  for (int k0 = 0; k0 < K; k0 += 32) {
#pragma unroll
    for (int j = 0; j < 2; ++j) {
      const int c  = j * 256 + t;        // 512 chunks of 16B each (8KB tile)
      const int r  = c >> 2;             // tile row 0..127
      const int cc = (c & 3) * 8;        // k offset in elements
      gload16(Ab + (long)r * K + k0 + cc, (char*)As + c * 16);
      gload16(Bb + (long)r * K + k0 + cc, (char*)Bs + c * 16);
    }
    __syncthreads();

    bf16x8 af[4], bf[4];
#pragma unroll
    for (int i = 0; i < 4; ++i) {
      af[i] = *(const bf16x8*)((const char*)As +
               (wr * 64 + i * 16 + (lane & 15)) * 64 + (lane >> 4) * 16);
      bf[i] = *(const bf16x8*)((const char*)Bs +
               (wc * 64 + i * 16 + (lane & 15)) * 64 + (lane >> 4) * 16);
    }
#pragma unroll
    for (int i = 0; i < 4; ++i)
#pragma unroll
      for (int n = 0; n < 4; ++n)
        acc[i][n] = __builtin_amdgcn_mfma_f32_16x16x32_bf16(af[i], bf[n], acc[i][n], 0, 0, 0);
    __syncthreads();
  }

  // Epilogue. D layout: col = lane&15, row = (lane>>4)*4 + j  [verified m89/m91]
#pragma unroll
  for (int i = 0; i < 4; ++i) {
#pragma unroll
    for (int n = 0; n < 4; ++n) {
      const long col = bcol + wc * 64 + n * 16 + (lane & 15);
      const float bb = bias[col];
#pragma unroll
      for (int j = 0; j < 4; ++j) {
        const long row = brow + wr * 64 + i * 16 + (lane >> 4) * 4 + j;
        float val = (acc[i][n][j] + bb) * out_scale;
        if (RELU) val = fmaxf(val, 0.f);
        const long idx = row * N + col;
        if (RESID) val += resid[idx];
        if (OUTBF) ((__bf16*)Cout)[idx] = (__bf16)val;
        else       ((float*)Cout)[idx]  = val;
      }
    }
  }
}

// ---------------------------------------------------------------------------
// Flash attention: per (b,h,qblk=64). KVBLK=64, 4 waves; each wave owns 16 q rows.
// Q,K,V,ctx global layout: [8192][1024] bf16, head h at cols h*64..h*64+63.
// Q pre-scaled by 1/8 in the Q-proj epilogue.
// ---------------------------------------------------------------------------
__global__ __launch_bounds__(256) void attn_kernel(const __bf16* __restrict__ Qg,
                                                   const __bf16* __restrict__ Kg,
                                                   const __bf16* __restrict__ Vg,
                                                   __bf16* __restrict__ Og) {
  __shared__ __align__(16) __bf16 Qs[64 * 64];   // [qrow][d]  128B rows
  __shared__ __align__(16) __bf16 Ks[64 * 64];   // [key][d]
  __shared__ __align__(16) __bf16 Vt[64 * 64];   // [d][key]
  __shared__ __align__(16) __bf16 Ps[4 * 16 * 64]; // per wave [qrow16][key64]

  const int t    = threadIdx.x;
  const int lane = t & 63;
  const int w    = t >> 6;
  const int b    = blockIdx.y >> 4;
  const int hh   = blockIdx.y & 15;
  const long row0 = (long)b * 1024 + (long)blockIdx.x * 64;
  const int col0  = hh * 64;

  // stage Q once (lane-linear LDS)
#pragma unroll
  for (int j = 0; j < 2; ++j) {
    const int c = j * 256 + t;     // 512 chunks: row = c/8, 16B piece = c%8
    const int r = c >> 3, cc = c & 7;
    gload16(Qg + (row0 + r) * E + col0 + cc * 8, (char*)Qs + c * 16);
  }

  f32x4 ctx[4];
  float m[4], l[4];
  const f32x4 z4 = {0.f, 0.f, 0.f, 0.f};
#pragma unroll
  for (int i = 0; i < 4; ++i) { ctx[i] = z4; m[i] = -INFINITY; l[i] = 0.f; }

  for (int kb = 0; kb < 16; ++kb) {
    __syncthreads();  // previous tile fully consumed
    const long krow0 = (long)b * 1024 + kb * 64;
#pragma unroll
    for (int j = 0; j < 2; ++j) {
      const int c = j * 256 + t;
      const int r = c >> 3, cc = c & 7;
      gload16(Kg + (krow0 + r) * E + col0 + cc * 8, (char*)Ks + c * 16);
    }
#pragma unroll
    for (int j = 0; j < 2; ++j) {  // V transposed into LDS: Vt[d][key]
      const int c = j * 256 + t;
      const int key = c >> 3, dc = c & 7;
      bf16x8 vv = *(const bf16x8*)(Vg + (krow0 + key) * E + col0 + dc * 8);
#pragma unroll
      for (int e = 0; e < 8; ++e) Vt[(dc * 8 + e) * 64 + key] = vv[e];
    }
    __syncthreads();

    // S = Q @ K^T  (k-dim = d = 64 -> 2 MFMA k-steps)
    f32x4 s[4];
#pragma unroll
    for (int nf = 0; nf < 4; ++nf) s[nf] = z4;
#pragma unroll
    for (int kk = 0; kk < 2; ++kk) {
      bf16x8 aq = *(const bf16x8*)((const char*)Qs +
                  (w * 16 + (lane & 15)) * 128 + kk * 64 + (lane >> 4) * 16);
#pragma unroll
      for (int nf = 0; nf < 4; ++nf) {
        bf16x8 bk = *(const bf16x8*)((const char*)Ks +
                    (nf * 16 + (lane & 15)) * 128 + kk * 64 + (lane >> 4) * 16);
        s[nf] = __builtin_amdgcn_mfma_f32_16x16x32_bf16(aq, bk, s[nf], 0, 0, 0);
      }
    }

    // online softmax. S layout: row=(lane>>4)*4+j, col=nf*16+(lane&15)
#pragma unroll
    for (int j = 0; j < 4; ++j) {
      float mx = fmaxf(fmaxf(s[0][j], s[1][j]), fmaxf(s[2][j], s[3][j]));
#pragma unroll
      for (int off = 1; off < 16; off <<= 1) mx = fmaxf(mx, __shfl_xor(mx, off, 16));
      const float mn   = fmaxf(m[j], mx);
      const float corr = __expf(m[j] - mn);
      float rs = 0.f;
#pragma unroll
      for (int nf = 0; nf < 4; ++nf) {
        const float p = __expf(s[nf][j] - mn);
        rs += p;
        Ps[w * 1024 + ((lane >> 4) * 4 + j) * 64 + nf * 16 + (lane & 15)] = (__bf16)p;
      }
#pragma unroll
      for (int off = 1; off < 16; off <<= 1) rs += __shfl_xor(rs, off, 16);
      l[j] = l[j] * corr + rs;
      m[j] = mn;
#pragma unroll
      for (int df = 0; df < 4; ++df) ctx[df][j] *= corr;
    }

    // ctx += P @ V  (k-dim = key = 64 -> 2 MFMA k-steps)
#pragma unroll
    for (int kk = 0; kk < 2; ++kk) {
      bf16x8 ap = *(const bf16x8*)((const char*)Ps +
                  w * 2048 + (lane & 15) * 128 + kk * 64 + (lane >> 4) * 16);
#pragma unroll
      for (int df = 0; df < 4; ++df) {
        bf16x8 bv = *(const bf16x8*)((const char*)Vt +
                    (df * 16 + (lane & 15)) * 128 + kk * 64 + (lane >> 4) * 16);
        ctx[df] = __builtin_amdgcn_mfma_f32_16x16x32_bf16(ap, bv, ctx[df], 0, 0, 0);
      }
    }
  }

  // normalize and write
#pragma unroll
  for (int df = 0; df < 4; ++df)
#pragma unroll
    for (int j = 0; j < 4; ++j) {
      const long row = row0 + w * 16 + (lane >> 4) * 4 + j;
      const int  col = col0 + df * 16 + (lane & 15);
      Og[row * E + col] = (__bf16)(ctx[df][j] / l[j]);
    }
}

// ---------------------------------------------------------------------------
extern "C" void kernel_launch(void* const* d_in, const int* in_sizes, int n_in,
                              void* d_out, int out_size, void* d_ws, size_t ws_size,
                              hipStream_t stream) {
  const float* x     = (const float*)d_in[0];
  const float* ln1g  = (const float*)d_in[1];
  const float* ln1b  = (const float*)d_in[2];
  const float* ln2g  = (const float*)d_in[3];
  const float* ln2b  = (const float*)d_in[4];
  const float* wq    = (const float*)d_in[5];
  const float* bq    = (const float*)d_in[6];
  const float* wk    = (const float*)d_in[7];
  const float* bk    = (const float*)d_in[8];
  const float* wv    = (const float*)d_in[9];
  const float* bv    = (const float*)d_in[10];
  const float* wo    = (const float*)d_in[11];
  const float* bo    = (const float*)d_in[12];
  const float* w1    = (const float*)d_in[13];
  const float* b1    = (const float*)d_in[14];
  const float* w2    = (const float*)d_in[15];
  const float* b2    = (const float*)d_in[16];
  float* out = (float*)d_out;

  char* ws = (char*)d_ws;
  const size_t MB = 1024 * 1024;
  __bf16* Wqt = (__bf16*)(ws + 0 * MB);     // [1024][1024] 2MB
  __bf16* Wkt = (__bf16*)(ws + 2 * MB);
  __bf16* Wvt = (__bf16*)(ws + 4 * MB);
  __bf16* Wot = (__bf16*)(ws + 6 * MB);
  __bf16* W1t = (__bf16*)(ws + 8 * MB);     // [4096][1024] 8MB
  __bf16* W2t = (__bf16*)(ws + 16 * MB);    // [1024][4096] 8MB
  __bf16* h   = (__bf16*)(ws + 24 * MB);    // [8192][1024] 16MB
  __bf16* qb  = (__bf16*)(ws + 40 * MB);    // 16MB
  __bf16* kb  = (__bf16*)(ws + 56 * MB);    // 16MB
  __bf16* vb  = (__bf16*)(ws + 72 * MB);    // 16MB
  __bf16* ctx = (__bf16*)(ws + 88 * MB);    // 16MB   (total 104MB)
  __bf16* ff1 = (__bf16*)(ws + 40 * MB);    // [8192][4096] 64MB, aliases q/k/v/ctx (dead by then)

  const dim3 blk(256);

  // weights -> bf16 transposed [N][K]
  wconv_kernel<<<dim3(E / 32, E / 32), blk, 0, stream>>>(wq, Wqt, E, E);
  wconv_kernel<<<dim3(E / 32, E / 32), blk, 0, stream>>>(wk, Wkt, E, E);
  wconv_kernel<<<dim3(E / 32, E / 32), blk, 0, stream>>>(wv, Wvt, E, E);
  wconv_kernel<<<dim3(E / 32, E / 32), blk, 0, stream>>>(wo, Wot, E, E);
  wconv_kernel<<<dim3(HID / 32, E / 32), blk, 0, stream>>>(w1, W1t, E, HID);
  wconv_kernel<<<dim3(E / 32, HID / 32), blk, 0, stream>>>(w2, W2t, HID, E);

  // LN1
  ln_kernel<<<TOK, blk, 0, stream>>>(x, ln1g, ln1b, h);

  // Q (scaled by 1/sqrt(64)=0.125), K, V projections
  gemm_kernel<false, false, true><<<dim3(E / 128, TOK / 128), blk, 0, stream>>>(
      h, Wqt, bq, nullptr, qb, TOK, E, E, 0.125f);
  gemm_kernel<false, false, true><<<dim3(E / 128, TOK / 128), blk, 0, stream>>>(
      h, Wkt, bk, nullptr, kb, TOK, E, E, 1.0f);
  gemm_kernel<false, false, true><<<dim3(E / 128, TOK / 128), blk, 0, stream>>>(
      h, Wvt, bv, nullptr, vb, TOK, E, E, 1.0f);

  // attention
  attn_kernel<<<dim3(16, 128), blk, 0, stream>>>(qb, kb, vb, ctx);

  // O projection + residual(x) -> d_out (fp32)
  gemm_kernel<false, true, false><<<dim3(E / 128, TOK / 128), blk, 0, stream>>>(
      ctx, Wot, bo, x, out, TOK, E, E, 1.0f);

  // LN2 on d_out
  ln_kernel<<<TOK, blk, 0, stream>>>(out, ln2g, ln2b, h);

  // FF1 with ReLU -> ff1 (bf16)
  gemm_kernel<true, false, true><<<dim3(HID / 128, TOK / 128), blk, 0, stream>>>(
      h, W1t, b1, nullptr, ff1, TOK, HID, E, 1.0f);

  // FF2 + residual(d_out) -> d_out (in-place, element-wise safe)
  gemm_kernel<false, true, false><<<dim3(E / 128, TOK / 128), blk, 0, stream>>>(
      ff1, W2t, b2, out, out, TOK, E, HID, 1.0f);
}

// Round 2
// 514.561 us; speedup vs baseline: 1.1838x; 1.1838x over previous
//
#include <hip/hip_runtime.h>
#include <hip/hip_bf16.h>

typedef __attribute__((ext_vector_type(4))) float f32x4;
typedef __attribute__((ext_vector_type(8))) __bf16 bf16x8;
typedef __attribute__((ext_vector_type(4))) __bf16 bf16x4;

static constexpr int E    = 1024;
static constexpr int TOK  = 8192;   // 8 * 1024 tokens
static constexpr int HID  = 4096;

#define DEVINL __device__ __forceinline__

// async global->LDS, 16B per lane. LDS dest must be lane-linear (wave base + lane*16).
DEVINL void gload16(const void* g, void* l) {
  __builtin_amdgcn_global_load_lds((__attribute__((address_space(1))) void*)g,
                                   (__attribute__((address_space(3))) void*)l, 16, 0, 0);
}

// ---------------------------------------------------------------------------
// Weight convert + transpose: W[K][N] f32 -> Wt[N][K] bf16 (32x32 LDS tiles)
// ---------------------------------------------------------------------------
__global__ __launch_bounds__(256) void wconv_kernel(const float* __restrict__ W,
                                                    __bf16* __restrict__ Wt,
                                                    int K, int N) {
  __shared__ float tile[32][33];
  const int t  = threadIdx.x;
  const long k0 = (long)blockIdx.y * 32;
  const long n0 = (long)blockIdx.x * 32;
  const int r  = t >> 3;
  const int c4 = (t & 7) * 4;
  float4 v = *(const float4*)&W[(k0 + r) * N + n0 + c4];
  tile[r][c4 + 0] = v.x; tile[r][c4 + 1] = v.y;
  tile[r][c4 + 2] = v.z; tile[r][c4 + 3] = v.w;
  __syncthreads();
  bf16x4 o;
#pragma unroll
  for (int i = 0; i < 4; ++i) o[i] = (__bf16)tile[c4 + i][r];
  *(bf16x4*)&Wt[(n0 + r) * K + k0 + c4] = o;
}

// ---------------------------------------------------------------------------
// LayerNorm (fp32 in) -> bf16 out. One block per row of 1024.
// ---------------------------------------------------------------------------
__global__ __launch_bounds__(256) void ln_kernel(const float* __restrict__ X,
                                                 const float* __restrict__ g,
                                                 const float* __restrict__ be,
                                                 __bf16* __restrict__ O) {
  const int t = threadIdx.x;
  const long row = blockIdx.x;
  float4 v = *(const float4*)&X[row * E + t * 4];
  float s  = v.x + v.y + v.z + v.w;
  float ss = v.x * v.x + v.y * v.y + v.z * v.z + v.w * v.w;
#pragma unroll
  for (int off = 32; off; off >>= 1) {
    s  += __shfl_down(s, off);
    ss += __shfl_down(ss, off);
  }
  __shared__ float red[8];
  const int w = t >> 6;
  if ((t & 63) == 0) { red[w] = s; red[4 + w] = ss; }
  __syncthreads();
  s  = red[0] + red[1] + red[2] + red[3];
  ss = red[4] + red[5] + red[6] + red[7];
  const float mean = s * (1.0f / E);
  const float var  = ss * (1.0f / E) - mean * mean;
  const float rstd = rsqrtf(var + 1e-5f);
  float4 gv = *(const float4*)&g[t * 4];
  float4 bv = *(const float4*)&be[t * 4];
  bf16x4 o;
  o[0] = (__bf16)((v.x - mean) * rstd * gv.x + bv.x);
  o[1] = (__bf16)((v.y - mean) * rstd * gv.y + bv.y);
  o[2] = (__bf16)((v.z - mean) * rstd * gv.z + bv.z);
  o[3] = (__bf16)((v.w - mean) * rstd * gv.w + bv.w);
  *(bf16x4*)&O[row * E + t * 4] = o;
}

// ---------------------------------------------------------------------------
// GEMM: C[M][N] = op(A[M][K] @ Bt[N][K]^T + bias) (+resid). bf16 MFMA 16x16x32.
// 128x128 block tile, BK=32, 4 waves (2x2), 64x64 per wave.
// NB=3: bias selected from {b0,b1,b2} by col>>10 (fused QKV, each seg 1024).
// ---------------------------------------------------------------------------
template <bool RELU, bool RESID, bool OUTBF, int NB>
__global__ __launch_bounds__(256) void gemm_kernel(const __bf16* __restrict__ A,
                                                   const __bf16* __restrict__ Bt,
                                                   const float* __restrict__ bias0,
                                                   const float* __restrict__ bias1,
                                                   const float* __restrict__ bias2,
                                                   const float* resid,
                                                   void* Cout,
                                                   int M, int N, int K) {
  __shared__ __align__(16) __bf16 As[128 * 32];  // [row][k] 64B rows
  __shared__ __align__(16) __bf16 Bs[128 * 32];  // [col][k]
  const int t    = threadIdx.x;
  const int lane = t & 63;
  const int wv   = t >> 6;
  const int wr   = wv >> 1;   // 0..1
  const int wc   = wv & 1;    // 0..1
  const long brow = (long)blockIdx.y * 128;
  const long bcol = (long)blockIdx.x * 128;

  f32x4 acc[4][4];
  const f32x4 z4 = {0.f, 0.f, 0.f, 0.f};
#pragma unroll
  for (int i = 0; i < 4; ++i)
#pragma unroll
    for (int n = 0; n < 4; ++n) acc[i][n] = z4;

  const __bf16* Ab = A  + brow * K;
  const __bf16* Bb = Bt + bcol * K;

  for (int k0 = 0; k0 < K; k0 += 32) {
#pragma unroll
    for (int j = 0; j < 2; ++j) {
      const int c  = j * 256 + t;        // 512 chunks of 16B each (8KB tile)
      const int r  = c >> 2;             // tile row 0..127
      const int cc = (c & 3) * 8;        // k offset in elements
      gload16(Ab + (long)r * K + k0 + cc, (char*)As + c * 16);
      gload16(Bb + (long)r * K + k0 + cc, (char*)Bs + c * 16);
    }
    __syncthreads();

    bf16x8 af[4], bf[4];
#pragma unroll
    for (int i = 0; i < 4; ++i) {
      af[i] = *(const bf16x8*)((const char*)As +
               (wr * 64 + i * 16 + (lane & 15)) * 64 + (lane >> 4) * 16);
      bf[i] = *(const bf16x8*)((const char*)Bs +
               (wc * 64 + i * 16 + (lane & 15)) * 64 + (lane >> 4) * 16);
    }
#pragma unroll
    for (int i = 0; i < 4; ++i)
#pragma unroll
      for (int n = 0; n < 4; ++n)
        acc[i][n] = __builtin_amdgcn_mfma_f32_16x16x32_bf16(af[i], bf[n], acc[i][n], 0, 0, 0);
    __syncthreads();
  }

  // Epilogue. D layout: col = lane&15, row = (lane>>4)*4 + j  [verified m89/m91]
#pragma unroll
  for (int i = 0; i < 4; ++i) {
#pragma unroll
    for (int n = 0; n < 4; ++n) {
      const long col = bcol + wc * 64 + n * 16 + (lane & 15);
      float bb;
      if (NB == 3) {
        const float* bp = (col < 1024) ? bias0 : ((col < 2048) ? bias1 : bias2);
        bb = bp[col & 1023];
      } else {
        bb = bias0[col];
      }
#pragma unroll
      for (int j = 0; j < 4; ++j) {
        const long row = brow + wr * 64 + i * 16 + (lane >> 4) * 4 + j;
        float val = acc[i][n][j] + bb;
        if (RELU) val = fmaxf(val, 0.f);
        const long idx = row * N + col;
        if (RESID) val += resid[idx];
        if (OUTBF) ((__bf16*)Cout)[idx] = (__bf16)val;
        else       ((float*)Cout)[idx]  = val;
      }
    }
  }
}

// ---------------------------------------------------------------------------
// Flash attention: per (b,h,qblk=64). KVBLK=64, 4 waves; each wave owns 16 q rows.
// Q/K/V in fused qkv buffer [8192][3072]; head h: Q cols h*64, K +1024, V +2048.
// S scaled by 1/8 in-register. All LDS tiles XOR-swizzled (16B piece granularity):
//   Qs/Ks/Ps: piece ^= (row & 7);  Vt: piece ^= (row&7)^((row>>3)&7).
// Q/K staged via global_load_lds with pre-swizzled SOURCE (LDS stays linear).
// ---------------------------------------------------------------------------
__global__ __launch_bounds__(256) void attn_kernel(const __bf16* __restrict__ QKV,
                                                   __bf16* __restrict__ Og) {
  __shared__ __align__(16) __bf16 Qs[64 * 64];     // [qrow][d]  128B rows, 8 pieces
  __shared__ __align__(16) __bf16 Ks[64 * 64];     // [key][d]
  __shared__ __align__(16) __bf16 Vt[64 * 64];     // [d][key]
  __shared__ __align__(16) __bf16 Ps[4 * 16 * 64]; // per wave [qrow16][key64]

  const int QSTR = 3072;
  const int t    = threadIdx.x;
  const int lane = t & 63;
  const int w    = t >> 6;
  const int b    = blockIdx.y >> 4;
  const int hh   = blockIdx.y & 15;
  const long row0 = (long)b * 1024 + (long)blockIdx.x * 64;
  const int colQ  = hh * 64;
  const int colK  = colQ + 1024;
  const int colV  = colQ + 2048;

  // stage Q once: LDS linear, global source piece pre-swizzled
#pragma unroll
  for (int j = 0; j < 2; ++j) {
    const int c = j * 256 + t;          // 512 chunks: row = c>>3, piece = c&7
    const int r = c >> 3;
    const int p = (c & 7) ^ (r & 7);    // source piece (XOR is an involution)
    gload16(QKV + (row0 + r) * QSTR + colQ + p * 8, (char*)Qs + c * 16);
  }

  f32x4 ctx[4];
  float m[4], l[4];
  const f32x4 z4 = {0.f, 0.f, 0.f, 0.f};
#pragma unroll
  for (int i = 0; i < 4; ++i) { ctx[i] = z4; m[i] = -INFINITY; l[i] = 0.f; }

  for (int kb = 0; kb < 16; ++kb) {
    __syncthreads();  // previous tile fully consumed (also covers initial Q stage)
    const long krow0 = (long)b * 1024 + kb * 64;
#pragma unroll
    for (int j = 0; j < 2; ++j) {
      const int c = j * 256 + t;
      const int r = c >> 3;
      const int p = (c & 7) ^ (r & 7);
      gload16(QKV + (krow0 + r) * QSTR + colK + p * 8, (char*)Ks + c * 16);
    }
#pragma unroll
    for (int j = 0; j < 2; ++j) {  // V transposed into LDS: Vt[d][key], swizzled
      const int c = j * 256 + t;
      const int key = c >> 3, dc = c & 7;
      bf16x8 vv = *(const bf16x8*)(QKV + (krow0 + key) * QSTR + colV + dc * 8);
#pragma unroll
      for (int e = 0; e < 8; ++e) {
        const int row = dc * 8 + e;
        const int sw  = (row & 7) ^ ((row >> 3) & 7);
        *(__bf16*)((char*)Vt + ((row * 128 + key * 2) ^ (sw << 4))) = vv[e];
      }
    }
    __syncthreads();

    // S = Q @ K^T  (k-dim = d = 64 -> 2 MFMA k-steps)
    f32x4 s[4];
#pragma unroll
    for (int nf = 0; nf < 4; ++nf) s[nf] = z4;
#pragma unroll
    for (int kk = 0; kk < 2; ++kk) {
      const int qrow = w * 16 + (lane & 15);
      const int qp   = (kk * 4 + (lane >> 4)) ^ (qrow & 7);
      bf16x8 aq = *(const bf16x8*)((const char*)Qs + qrow * 128 + qp * 16);
#pragma unroll
      for (int nf = 0; nf < 4; ++nf) {
        const int krow = nf * 16 + (lane & 15);
        const int kp   = (kk * 4 + (lane >> 4)) ^ (krow & 7);
        bf16x8 bk = *(const bf16x8*)((const char*)Ks + krow * 128 + kp * 16);
        s[nf] = __builtin_amdgcn_mfma_f32_16x16x32_bf16(aq, bk, s[nf], 0, 0, 0);
      }
    }
    // fold the 1/sqrt(head_dim)=1/8 scale here
#pragma unroll
    for (int nf = 0; nf < 4; ++nf)
#pragma unroll
      for (int j = 0; j < 4; ++j) s[nf][j] *= 0.125f;

    // online softmax. S layout: row=(lane>>4)*4+j, col=nf*16+(lane&15)
#pragma unroll
    for (int j = 0; j < 4; ++j) {
      float mx = fmaxf(fmaxf(s[0][j], s[1][j]), fmaxf(s[2][j], s[3][j]));
#pragma unroll
      for (int off = 1; off < 16; off <<= 1) mx = fmaxf(mx, __shfl_xor(mx, off, 16));
      const float mn   = fmaxf(m[j], mx);
      const float corr = __expf(m[j] - mn);
      float rs = 0.f;
      const int prow = (lane >> 4) * 4 + j;
#pragma unroll
      for (int nf = 0; nf < 4; ++nf) {
        const float p = __expf(s[nf][j] - mn);
        rs += p;
        const int col = nf * 16 + (lane & 15);
        *(__bf16*)((char*)Ps + w * 2048 +
                   ((prow * 128 + col * 2) ^ ((prow & 7) << 4))) = (__bf16)p;
      }
#pragma unroll
      for (int off = 1; off < 16; off <<= 1) rs += __shfl_xor(rs, off, 16);
      l[j] = l[j] * corr + rs;
      m[j] = mn;
#pragma unroll
      for (int df = 0; df < 4; ++df) ctx[df][j] *= corr;
    }

    // ctx += P @ V  (k-dim = key = 64 -> 2 MFMA k-steps)
#pragma unroll
    for (int kk = 0; kk < 2; ++kk) {
      const int prow = lane & 15;
      const int pp   = (kk * 4 + (lane >> 4)) ^ (prow & 7);
      bf16x8 ap = *(const bf16x8*)((const char*)Ps + w * 2048 + prow * 128 + pp * 16);
#pragma unroll
      for (int df = 0; df < 4; ++df) {
        const int vrow = df * 16 + (lane & 15);
        const int sw   = (vrow & 7) ^ ((vrow >> 3) & 7);
        const int vp   = (kk * 4 + (lane >> 4)) ^ sw;
        bf16x8 bv = *(const bf16x8*)((const char*)Vt + vrow * 128 + vp * 16);
        ctx[df] = __builtin_amdgcn_mfma_f32_16x16x32_bf16(ap, bv, ctx[df], 0, 0, 0);
      }
    }
  }

  // normalize and write (ctx buffer stride 1024)
#pragma unroll
  for (int df = 0; df < 4; ++df)
#pragma unroll
    for (int j = 0; j < 4; ++j) {
      const long row = row0 + w * 16 + (lane >> 4) * 4 + j;
      const int  col = colQ + df * 16 + (lane & 15);
      Og[row * E + col] = (__bf16)(ctx[df][j] / l[j]);
    }
}

// ---------------------------------------------------------------------------
extern "C" void kernel_launch(void* const* d_in, const int* in_sizes, int n_in,
                              void* d_out, int out_size, void* d_ws, size_t ws_size,
                              hipStream_t stream) {
  const float* x     = (const float*)d_in[0];
  const float* ln1g  = (const float*)d_in[1];
  const float* ln1b  = (const float*)d_in[2];
  const float* ln2g  = (const float*)d_in[3];
  const float* ln2b  = (const float*)d_in[4];
  const float* wq    = (const float*)d_in[5];
  const float* bq    = (const float*)d_in[6];
  const float* wk    = (const float*)d_in[7];
  const float* bk    = (const float*)d_in[8];
  const float* wv    = (const float*)d_in[9];
  const float* bv    = (const float*)d_in[10];
  const float* wo    = (const float*)d_in[11];
  const float* bo    = (const float*)d_in[12];
  const float* w1    = (const float*)d_in[13];
  const float* b1    = (const float*)d_in[14];
  const float* w2    = (const float*)d_in[15];
  const float* b2    = (const float*)d_in[16];
  float* out = (float*)d_out;

  char* ws = (char*)d_ws;
  const size_t MB = 1024 * 1024;
  __bf16* Wqkv = (__bf16*)(ws + 0 * MB);    // [3072][1024] bf16, 6MB (q|k|v rows)
  __bf16* Wot  = (__bf16*)(ws + 6 * MB);    // [1024][1024] 2MB
  __bf16* W1t  = (__bf16*)(ws + 8 * MB);    // [4096][1024] 8MB
  __bf16* W2t  = (__bf16*)(ws + 16 * MB);   // [1024][4096] 8MB
  __bf16* h    = (__bf16*)(ws + 24 * MB);   // [8192][1024] 16MB
  __bf16* qkv  = (__bf16*)(ws + 40 * MB);   // [8192][3072] 48MB
  __bf16* ctx  = (__bf16*)(ws + 88 * MB);   // [8192][1024] 16MB (total 104MB)
  __bf16* ff1  = (__bf16*)(ws + 40 * MB);   // [8192][4096] 64MB, aliases qkv (dead)

  const dim3 blk(256);

  // weights -> bf16 transposed [N][K]; q/k/v stacked into Wqkv
  wconv_kernel<<<dim3(E / 32, E / 32), blk, 0, stream>>>(wq, Wqkv, E, E);
  wconv_kernel<<<dim3(E / 32, E / 32), blk, 0, stream>>>(wk, Wqkv + 1024 * 1024, E, E);
  wconv_kernel<<<dim3(E / 32, E / 32), blk, 0, stream>>>(wv, Wqkv + 2048 * 1024, E, E);
  wconv_kernel<<<dim3(E / 32, E / 32), blk, 0, stream>>>(wo, Wot, E, E);
  wconv_kernel<<<dim3(HID / 32, E / 32), blk, 0, stream>>>(w1, W1t, E, HID);
  wconv_kernel<<<dim3(E / 32, HID / 32), blk, 0, stream>>>(w2, W2t, HID, E);

  // LN1
  ln_kernel<<<TOK, blk, 0, stream>>>(x, ln1g, ln1b, h);

  // fused QKV projection: [8192][3072]
  gemm_kernel<false, false, true, 3><<<dim3(3072 / 128, TOK / 128), blk, 0, stream>>>(
      h, Wqkv, bq, bk, bv, nullptr, qkv, TOK, 3072, E);

  // attention
  attn_kernel<<<dim3(16, 128), blk, 0, stream>>>(qkv, ctx);

  // O projection + residual(x) -> d_out (fp32)
  gemm_kernel<false, true, false, 1><<<dim3(E / 128, TOK / 128), blk, 0, stream>>>(
      ctx, Wot, bo, nullptr, nullptr, x, out, TOK, E, E);

  // LN2 on d_out
  ln_kernel<<<TOK, blk, 0, stream>>>(out, ln2g, ln2b, h);

  // FF1 with ReLU -> ff1 (bf16)
  gemm_kernel<true, false, true, 1><<<dim3(HID / 128, TOK / 128), blk, 0, stream>>>(
      h, W1t, b1, nullptr, nullptr, nullptr, ff1, TOK, HID, E);

  // FF2 + residual(d_out) -> d_out (in-place, element-wise safe)
  gemm_kernel<false, true, false, 1><<<dim3(E / 128, TOK / 128), blk, 0, stream>>>(
      ff1, W2t, b2, nullptr, nullptr, out, out, TOK, E, HID);
}

// Round 3
// 432.867 us; speedup vs baseline: 1.4072x; 1.1887x over previous
//
#include <hip/hip_runtime.h>
#include <hip/hip_bf16.h>

typedef __attribute__((ext_vector_type(4))) float f32x4;
typedef __attribute__((ext_vector_type(8))) __bf16 bf16x8;
typedef __attribute__((ext_vector_type(4))) __bf16 bf16x4;

static constexpr int E    = 1024;
static constexpr int TOK  = 8192;   // 8 * 1024 tokens
static constexpr int HID  = 4096;

#define DEVINL __device__ __forceinline__

// async global->LDS, 16B per lane. LDS dest must be lane-linear (wave base + lane*16).
DEVINL void gload16(const void* g, void* l) {
  __builtin_amdgcn_global_load_lds((__attribute__((address_space(1))) void*)g,
                                   (__attribute__((address_space(3))) void*)l, 16, 0, 0);
}

// ---------------------------------------------------------------------------
// Weight convert + transpose: W[K][N] f32 -> Wt[N][K] bf16 (32x32 LDS tiles)
// ---------------------------------------------------------------------------
__global__ __launch_bounds__(256) void wconv_kernel(const float* __restrict__ W,
                                                    __bf16* __restrict__ Wt,
                                                    int K, int N) {
  __shared__ float tile[32][33];
  const int t  = threadIdx.x;
  const long k0 = (long)blockIdx.y * 32;
  const long n0 = (long)blockIdx.x * 32;
  const int r  = t >> 3;
  const int c4 = (t & 7) * 4;
  float4 v = *(const float4*)&W[(k0 + r) * N + n0 + c4];
  tile[r][c4 + 0] = v.x; tile[r][c4 + 1] = v.y;
  tile[r][c4 + 2] = v.z; tile[r][c4 + 3] = v.w;
  __syncthreads();
  bf16x4 o;
#pragma unroll
  for (int i = 0; i < 4; ++i) o[i] = (__bf16)tile[c4 + i][r];
  *(bf16x4*)&Wt[(n0 + r) * K + k0 + c4] = o;
}

// ---------------------------------------------------------------------------
// LayerNorm (fp32 in) -> bf16 out. One block per row of 1024.
// ---------------------------------------------------------------------------
__global__ __launch_bounds__(256) void ln_kernel(const float* __restrict__ X,
                                                 const float* __restrict__ g,
                                                 const float* __restrict__ be,
                                                 __bf16* __restrict__ O) {
  const int t = threadIdx.x;
  const long row = blockIdx.x;
  float4 v = *(const float4*)&X[row * E + t * 4];
  float s  = v.x + v.y + v.z + v.w;
  float ss = v.x * v.x + v.y * v.y + v.z * v.z + v.w * v.w;
#pragma unroll
  for (int off = 32; off; off >>= 1) {
    s  += __shfl_down(s, off);
    ss += __shfl_down(ss, off);
  }
  __shared__ float red[8];
  const int w = t >> 6;
  if ((t & 63) == 0) { red[w] = s; red[4 + w] = ss; }
  __syncthreads();
  s  = red[0] + red[1] + red[2] + red[3];
  ss = red[4] + red[5] + red[6] + red[7];
  const float mean = s * (1.0f / E);
  const float var  = ss * (1.0f / E) - mean * mean;
  const float rstd = rsqrtf(var + 1e-5f);
  float4 gv = *(const float4*)&g[t * 4];
  float4 bv = *(const float4*)&be[t * 4];
  bf16x4 o;
  o[0] = (__bf16)((v.x - mean) * rstd * gv.x + bv.x);
  o[1] = (__bf16)((v.y - mean) * rstd * gv.y + bv.y);
  o[2] = (__bf16)((v.z - mean) * rstd * gv.z + bv.z);
  o[3] = (__bf16)((v.w - mean) * rstd * gv.w + bv.w);
  *(bf16x4*)&O[row * E + t * 4] = o;
}

// ---------------------------------------------------------------------------
// Deep-pipelined GEMM: C[M][N] = op(A[M][K] @ Bt[N][K]^T + bias) (+resid).
// BM=256, BN=128, BK=64. 512 threads = 8 waves (2 wr x 4 wc); per-wave 128x32.
// 3 LDS buffers (A 32KB + B 16KB each = 144KB), stage-ahead-2, counted vmcnt(6)
// once per K-tile (never 0 in loop), raw s_barrier (no implicit drain),
// T2 XOR swizzle: piece ^= (row&7); staged via pre-swizzled global source.
// Per K-tile: ph0 {read A m0-3 + all B (12 ds_read_b128), issue A0+B of t+2,
// 16 MFMA}, ph1 {read A m4-7 (8), issue A1 of t+2, 16 MFMA, vmcnt(6), barrier}.
// ---------------------------------------------------------------------------
#define ABAR()  asm volatile("s_barrier" ::: "memory")
#define AVM(n)  asm volatile("s_waitcnt vmcnt(" #n ")" ::: "memory")

template <bool RELU, bool RESID, bool OUTBF, int NB>
__global__ __launch_bounds__(512, 2) void gemm8_kernel(const __bf16* __restrict__ A,
                                                       const __bf16* __restrict__ Bt,
                                                       const float* __restrict__ bias0,
                                                       const float* __restrict__ bias1,
                                                       const float* __restrict__ bias2,
                                                       const float* resid,
                                                       void* Cout,
                                                       int M, int N, int K) {
  extern __shared__ char lds[];   // 3 * (32768 A + 16384 B) = 147456 B
  const int tid  = threadIdx.x;
  const int lane = tid & 63;
  const int l15  = lane & 15;
  const int wid  = tid >> 6;
  const int wr   = wid >> 2;   // 0..1
  const int wc   = wid & 3;    // 0..3

  // XCD-aware swizzle (all grids have nwg % 8 == 0)
  const int nwg  = gridDim.x * gridDim.y;
  const int flat = blockIdx.x + gridDim.x * blockIdx.y;
  const int swz  = (flat & 7) * (nwg >> 3) + (flat >> 3);
  const int bx   = swz % gridDim.x;
  const int by   = swz / gridDim.x;
  const long brow = (long)by * 256;
  const long bcol = (long)bx * 128;

  const __bf16* Ab = A  + brow * K;
  const __bf16* Bb = Bt + bcol * K;
  const int NT = K >> 6;

  char* bA0 = lds;
  char* bA1 = lds + 49152;
  char* bA2 = lds + 98304;
  // B base = A base + 32768

  // ---- staging helpers (inline) ----
  // A half: two 64-row segments; LDS linear in tid within each segment.
  auto stageA = [&](int k0, char* base, int seg0, int seg1) {
    {
      const int r = seg0 + (tid >> 3);
      const int p = (tid & 7) ^ (r & 7);
      gload16(Ab + (long)r * K + k0 + p * 8, base + seg0 * 128 + tid * 16);
    }
    {
      const int r = seg1 + (tid >> 3);
      const int p = (tid & 7) ^ (r & 7);
      gload16(Ab + (long)r * K + k0 + p * 8, base + seg1 * 128 + tid * 16);
    }
  };
  auto stageB = [&](int k0, char* base) {
#pragma unroll
    for (int i = 0; i < 2; ++i) {
      const int c = i * 64 + (tid >> 3);
      const int p = (tid & 7) ^ (c & 7);
      gload16(Bb + (long)c * K + k0 + p * 8, base + 32768 + i * 8192 + tid * 16);
    }
  };

  f32x4 acc[8][2];
  const f32x4 z4 = {0.f, 0.f, 0.f, 0.f};
#pragma unroll
  for (int m = 0; m < 8; ++m) { acc[m][0] = z4; acc[m][1] = z4; }

  // ---- prologue: tile0 -> bA0, tile1 -> bA1 (12 loads); wait tile0 ----
  stageA(0, bA0, 0, 128);
  stageA(0, bA0, 64, 192);
  stageB(0, bA0);
  stageA(64, bA1, 0, 128);
  stageA(64, bA1, 64, 192);
  stageB(64, bA1);
  AVM(6);
  ABAR();

  for (int t = 0; t < NT; ++t) {
    const int k2 = (t + 2 < NT) ? ((t + 2) << 6) : 0;

    // ---- phase 0: ds_read A m0-3 + all B; issue A-half0 + B of t+2 ----
    bf16x8 af[4][2], bfr[2][2];
#pragma unroll
    for (int m = 0; m < 4; ++m)
#pragma unroll
      for (int kk = 0; kk < 2; ++kk) {
        const int row = wr * 128 + m * 16 + l15;
        const int p   = ((kk << 2) + (lane >> 4)) ^ (row & 7);
        af[m][kk] = *(const bf16x8*)(bA0 + row * 128 + p * 16);
      }
#pragma unroll
    for (int n = 0; n < 2; ++n)
#pragma unroll
      for (int kk = 0; kk < 2; ++kk) {
        const int col = wc * 32 + n * 16 + l15;
        const int p   = ((kk << 2) + (lane >> 4)) ^ (col & 7);
        bfr[n][kk] = *(const bf16x8*)(bA0 + 32768 + col * 128 + p * 16);
      }
    stageA(k2, bA2, 0, 128);
    stageB(k2, bA2);
    ABAR();
    __builtin_amdgcn_s_setprio(1);
#pragma unroll
    for (int m = 0; m < 4; ++m)
#pragma unroll
      for (int n = 0; n < 2; ++n) {
        acc[m][n] = __builtin_amdgcn_mfma_f32_16x16x32_bf16(af[m][0], bfr[n][0], acc[m][n], 0, 0, 0);
        acc[m][n] = __builtin_amdgcn_mfma_f32_16x16x32_bf16(af[m][1], bfr[n][1], acc[m][n], 0, 0, 0);
      }
    __builtin_amdgcn_s_setprio(0);
    ABAR();

    // ---- phase 1: ds_read A m4-7; issue A-half1 of t+2 ----
#pragma unroll
    for (int m = 0; m < 4; ++m)
#pragma unroll
      for (int kk = 0; kk < 2; ++kk) {
        const int row = wr * 128 + (m + 4) * 16 + l15;
        const int p   = ((kk << 2) + (lane >> 4)) ^ (row & 7);
        af[m][kk] = *(const bf16x8*)(bA0 + row * 128 + p * 16);
      }
    stageA(k2, bA2, 64, 192);
    ABAR();
    __builtin_amdgcn_s_setprio(1);
#pragma unroll
    for (int m = 0; m < 4; ++m)
#pragma unroll
      for (int n = 0; n < 2; ++n) {
        acc[m + 4][n] = __builtin_amdgcn_mfma_f32_16x16x32_bf16(af[m][0], bfr[n][0], acc[m + 4][n], 0, 0, 0);
        acc[m + 4][n] = __builtin_amdgcn_mfma_f32_16x16x32_bf16(af[m][1], bfr[n][1], acc[m + 4][n], 0, 0, 0);
      }
    __builtin_amdgcn_s_setprio(0);
    AVM(6);     // tile t+1 fully landed (its 6 loads were issued during iter t-1)
    ABAR();     // publish to all waves before next iter's ds_reads

    // rotate buffers
    char* tmp = bA0; bA0 = bA1; bA1 = bA2; bA2 = tmp;
  }
  AVM(0);  // drain in-flight LDS DMA before using/ending

  // ---- epilogue. D layout: col = lane&15, row = (lane>>4)*4 + j ----
#pragma unroll
  for (int m = 0; m < 8; ++m) {
#pragma unroll
    for (int n = 0; n < 2; ++n) {
      const long col = bcol + wc * 32 + n * 16 + l15;
      float bb;
      if (NB == 3) {
        const float* bp = (col < 1024) ? bias0 : ((col < 2048) ? bias1 : bias2);
        bb = bp[col & 1023];
      } else {
        bb = bias0[col];
      }
#pragma unroll
      for (int j = 0; j < 4; ++j) {
        const long row = brow + wr * 128 + m * 16 + (lane >> 4) * 4 + j;
        float val = acc[m][n][j] + bb;
        if (RELU) val = fmaxf(val, 0.f);
        const long idx = row * N + col;
        if (RESID) val += resid[idx];
        if (OUTBF) ((__bf16*)Cout)[idx] = (__bf16)val;
        else       ((float*)Cout)[idx]  = val;
      }
    }
  }
}

// ---------------------------------------------------------------------------
// Flash attention: per (b,h,qblk=64). KVBLK=64, 4 waves; each wave owns 16 q rows.
// Q/K/V in fused qkv buffer [8192][3072]; head h: Q cols h*64, K +1024, V +2048.
// S scaled by 1/8 in-register. All LDS tiles XOR-swizzled (16B piece granularity).
// ---------------------------------------------------------------------------
__global__ __launch_bounds__(256) void attn_kernel(const __bf16* __restrict__ QKV,
                                                   __bf16* __restrict__ Og) {
  __shared__ __align__(16) __bf16 Qs[64 * 64];     // [qrow][d]  128B rows, 8 pieces
  __shared__ __align__(16) __bf16 Ks[64 * 64];     // [key][d]
  __shared__ __align__(16) __bf16 Vt[64 * 64];     // [d][key]
  __shared__ __align__(16) __bf16 Ps[4 * 16 * 64]; // per wave [qrow16][key64]

  const int QSTR = 3072;
  const int t    = threadIdx.x;
  const int lane = t & 63;
  const int w    = t >> 6;
  const int b    = blockIdx.y >> 4;
  const int hh   = blockIdx.y & 15;
  const long row0 = (long)b * 1024 + (long)blockIdx.x * 64;
  const int colQ  = hh * 64;
  const int colK  = colQ + 1024;
  const int colV  = colQ + 2048;

  // stage Q once: LDS linear, global source piece pre-swizzled
#pragma unroll
  for (int j = 0; j < 2; ++j) {
    const int c = j * 256 + t;          // 512 chunks: row = c>>3, piece = c&7
    const int r = c >> 3;
    const int p = (c & 7) ^ (r & 7);    // source piece (XOR is an involution)
    gload16(QKV + (row0 + r) * QSTR + colQ + p * 8, (char*)Qs + c * 16);
  }

  f32x4 ctx[4];
  float m[4], l[4];
  const f32x4 z4 = {0.f, 0.f, 0.f, 0.f};
#pragma unroll
  for (int i = 0; i < 4; ++i) { ctx[i] = z4; m[i] = -INFINITY; l[i] = 0.f; }

  for (int kb = 0; kb < 16; ++kb) {
    __syncthreads();  // previous tile fully consumed (also covers initial Q stage)
    const long krow0 = (long)b * 1024 + kb * 64;
#pragma unroll
    for (int j = 0; j < 2; ++j) {
      const int c = j * 256 + t;
      const int r = c >> 3;
      const int p = (c & 7) ^ (r & 7);
      gload16(QKV + (krow0 + r) * QSTR + colK + p * 8, (char*)Ks + c * 16);
    }
#pragma unroll
    for (int j = 0; j < 2; ++j) {  // V transposed into LDS: Vt[d][key], swizzled
      const int c = j * 256 + t;
      const int key = c >> 3, dc = c & 7;
      bf16x8 vv = *(const bf16x8*)(QKV + (krow0 + key) * QSTR + colV + dc * 8);
#pragma unroll
      for (int e = 0; e < 8; ++e) {
        const int row = dc * 8 + e;
        const int sw  = (row & 7) ^ ((row >> 3) & 7);
        *(__bf16*)((char*)Vt + ((row * 128 + key * 2) ^ (sw << 4))) = vv[e];
      }
    }
    __syncthreads();

    // S = Q @ K^T  (k-dim = d = 64 -> 2 MFMA k-steps)
    f32x4 s[4];
#pragma unroll
    for (int nf = 0; nf < 4; ++nf) s[nf] = z4;
#pragma unroll
    for (int kk = 0; kk < 2; ++kk) {
      const int qrow = w * 16 + (lane & 15);
      const int qp   = (kk * 4 + (lane >> 4)) ^ (qrow & 7);
      bf16x8 aq = *(const bf16x8*)((const char*)Qs + qrow * 128 + qp * 16);
#pragma unroll
      for (int nf = 0; nf < 4; ++nf) {
        const int krow = nf * 16 + (lane & 15);
        const int kp   = (kk * 4 + (lane >> 4)) ^ (krow & 7);
        bf16x8 bk = *(const bf16x8*)((const char*)Ks + krow * 128 + kp * 16);
        s[nf] = __builtin_amdgcn_mfma_f32_16x16x32_bf16(aq, bk, s[nf], 0, 0, 0);
      }
    }
    // fold the 1/sqrt(head_dim)=1/8 scale here
#pragma unroll
    for (int nf = 0; nf < 4; ++nf)
#pragma unroll
      for (int j = 0; j < 4; ++j) s[nf][j] *= 0.125f;

    // online softmax. S layout: row=(lane>>4)*4+j, col=nf*16+(lane&15)
#pragma unroll
    for (int j = 0; j < 4; ++j) {
      float mx = fmaxf(fmaxf(s[0][j], s[1][j]), fmaxf(s[2][j], s[3][j]));
#pragma unroll
      for (int off = 1; off < 16; off <<= 1) mx = fmaxf(mx, __shfl_xor(mx, off, 16));
      const float mn   = fmaxf(m[j], mx);
      const float corr = __expf(m[j] - mn);
      float rs = 0.f;
      const int prow = (lane >> 4) * 4 + j;
#pragma unroll
      for (int nf = 0; nf < 4; ++nf) {
        const float p = __expf(s[nf][j] - mn);
        rs += p;
        const int col = nf * 16 + (lane & 15);
        *(__bf16*)((char*)Ps + w * 2048 +
                   ((prow * 128 + col * 2) ^ ((prow & 7) << 4))) = (__bf16)p;
      }
#pragma unroll
      for (int off = 1; off < 16; off <<= 1) rs += __shfl_xor(rs, off, 16);
      l[j] = l[j] * corr + rs;
      m[j] = mn;
#pragma unroll
      for (int df = 0; df < 4; ++df) ctx[df][j] *= corr;
    }

    // ctx += P @ V  (k-dim = key = 64 -> 2 MFMA k-steps)
#pragma unroll
    for (int kk = 0; kk < 2; ++kk) {
      const int prow = lane & 15;
      const int pp   = (kk * 4 + (lane >> 4)) ^ (prow & 7);
      bf16x8 ap = *(const bf16x8*)((const char*)Ps + w * 2048 + prow * 128 + pp * 16);
#pragma unroll
      for (int df = 0; df < 4; ++df) {
        const int vrow = df * 16 + (lane & 15);
        const int sw   = (vrow & 7) ^ ((vrow >> 3) & 7);
        const int vp   = (kk * 4 + (lane >> 4)) ^ sw;
        bf16x8 bv = *(const bf16x8*)((const char*)Vt + vrow * 128 + vp * 16);
        ctx[df] = __builtin_amdgcn_mfma_f32_16x16x32_bf16(ap, bv, ctx[df], 0, 0, 0);
      }
    }
  }

  // normalize and write (ctx buffer stride 1024)
#pragma unroll
  for (int df = 0; df < 4; ++df)
#pragma unroll
    for (int j = 0; j < 4; ++j) {
      const long row = row0 + w * 16 + (lane >> 4) * 4 + j;
      const int  col = colQ + df * 16 + (lane & 15);
      Og[row * E + col] = (__bf16)(ctx[df][j] / l[j]);
    }
}

// ---------------------------------------------------------------------------
extern "C" void kernel_launch(void* const* d_in, const int* in_sizes, int n_in,
                              void* d_out, int out_size, void* d_ws, size_t ws_size,
                              hipStream_t stream) {
  const float* x     = (const float*)d_in[0];
  const float* ln1g  = (const float*)d_in[1];
  const float* ln1b  = (const float*)d_in[2];
  const float* ln2g  = (const float*)d_in[3];
  const float* ln2b  = (const float*)d_in[4];
  const float* wq    = (const float*)d_in[5];
  const float* bq    = (const float*)d_in[6];
  const float* wk    = (const float*)d_in[7];
  const float* bk    = (const float*)d_in[8];
  const float* wv    = (const float*)d_in[9];
  const float* bv    = (const float*)d_in[10];
  const float* wo    = (const float*)d_in[11];
  const float* bo    = (const float*)d_in[12];
  const float* w1    = (const float*)d_in[13];
  const float* b1    = (const float*)d_in[14];
  const float* w2    = (const float*)d_in[15];
  const float* b2    = (const float*)d_in[16];
  float* out = (float*)d_out;

  char* ws = (char*)d_ws;
  const size_t MB = 1024 * 1024;
  __bf16* Wqkv = (__bf16*)(ws + 0 * MB);    // [3072][1024] bf16, 6MB (q|k|v rows)
  __bf16* Wot  = (__bf16*)(ws + 6 * MB);    // [1024][1024] 2MB
  __bf16* W1t  = (__bf16*)(ws + 8 * MB);    // [4096][1024] 8MB
  __bf16* W2t  = (__bf16*)(ws + 16 * MB);   // [1024][4096] 8MB
  __bf16* h    = (__bf16*)(ws + 24 * MB);   // [8192][1024] 16MB
  __bf16* qkv  = (__bf16*)(ws + 40 * MB);   // [8192][3072] 48MB
  __bf16* ctx  = (__bf16*)(ws + 88 * MB);   // [8192][1024] 16MB (total 104MB)
  __bf16* ff1  = (__bf16*)(ws + 40 * MB);   // [8192][4096] 64MB, aliases qkv (dead)

  const dim3 blk(256);
  const dim3 blk512(512);
  const size_t GLDS = 147456;               // 3 * (32KB A + 16KB B)

  // weights -> bf16 transposed [N][K]; q/k/v stacked into Wqkv
  wconv_kernel<<<dim3(E / 32, E / 32), blk, 0, stream>>>(wq, Wqkv, E, E);
  wconv_kernel<<<dim3(E / 32, E / 32), blk, 0, stream>>>(wk, Wqkv + 1024 * 1024, E, E);
  wconv_kernel<<<dim3(E / 32, E / 32), blk, 0, stream>>>(wv, Wqkv + 2048 * 1024, E, E);
  wconv_kernel<<<dim3(E / 32, E / 32), blk, 0, stream>>>(wo, Wot, E, E);
  wconv_kernel<<<dim3(HID / 32, E / 32), blk, 0, stream>>>(w1, W1t, E, HID);
  wconv_kernel<<<dim3(E / 32, HID / 32), blk, 0, stream>>>(w2, W2t, HID, E);

  // LN1
  ln_kernel<<<TOK, blk, 0, stream>>>(x, ln1g, ln1b, h);

  // fused QKV projection: [8192][3072]   (grid 24x32 = 768 blocks)
  gemm8_kernel<false, false, true, 3><<<dim3(3072 / 128, TOK / 256), blk512, GLDS, stream>>>(
      h, Wqkv, bq, bk, bv, nullptr, qkv, TOK, 3072, E);

  // attention
  attn_kernel<<<dim3(16, 128), blk, 0, stream>>>(qkv, ctx);

  // O projection + residual(x) -> d_out (fp32)   (grid 8x32 = 256 blocks)
  gemm8_kernel<false, true, false, 1><<<dim3(E / 128, TOK / 256), blk512, GLDS, stream>>>(
      ctx, Wot, bo, nullptr, nullptr, x, out, TOK, E, E);

  // LN2 on d_out
  ln_kernel<<<TOK, blk, 0, stream>>>(out, ln2g, ln2b, h);

  // FF1 with ReLU -> ff1 (bf16)   (grid 32x32 = 1024 blocks)
  gemm8_kernel<true, false, true, 1><<<dim3(HID / 128, TOK / 256), blk512, GLDS, stream>>>(
      h, W1t, b1, nullptr, nullptr, nullptr, ff1, TOK, HID, E);

  // FF2 + residual(d_out) -> d_out (in-place, element-wise safe)
  gemm8_kernel<false, true, false, 1><<<dim3(E / 128, TOK / 256), blk512, GLDS, stream>>>(
      ff1, W2t, b2, nullptr, nullptr, out, out, TOK, E, HID);
}

// Round 4
// 371.335 us; speedup vs baseline: 1.6404x; 1.1657x over previous
//
#include <hip/hip_runtime.h>
#include <hip/hip_bf16.h>

typedef __attribute__((ext_vector_type(4))) float f32x4;
typedef __attribute__((ext_vector_type(16))) float f32x16;
typedef __attribute__((ext_vector_type(8))) __bf16 bf16x8;
typedef __attribute__((ext_vector_type(4))) __bf16 bf16x4;
typedef __attribute__((ext_vector_type(4))) unsigned int u32x4;

static constexpr int E    = 1024;
static constexpr int TOK  = 8192;   // 8 * 1024 tokens
static constexpr int HID  = 4096;

#define DEVINL __device__ __forceinline__

// async global->LDS, 16B per lane. LDS dest must be lane-linear (wave base + lane*16).
DEVINL void gload16(const void* g, void* l) {
  __builtin_amdgcn_global_load_lds((__attribute__((address_space(1))) void*)g,
                                   (__attribute__((address_space(3))) void*)l, 16, 0, 0);
}

#define ABAR()  asm volatile("s_barrier" ::: "memory")
#define AVM(n)  asm volatile("s_waitcnt vmcnt(" #n ")" ::: "memory")
#define CVTPK(dst, lo, hi) asm("v_cvt_pk_bf16_f32 %0, %1, %2" : "=v"(dst) : "v"(lo), "v"(hi))
#define PLSWAP(a, b) asm("v_permlane32_swap_b32 %0, %1" : "+v"(a), "+v"(b))

// ---------------------------------------------------------------------------
// Weight convert + transpose: W[K][N] f32 -> Wt[N][K] bf16 (32x32 LDS tiles)
// ---------------------------------------------------------------------------
__global__ __launch_bounds__(256) void wconv_kernel(const float* __restrict__ W,
                                                    __bf16* __restrict__ Wt,
                                                    int K, int N) {
  __shared__ float tile[32][33];
  const int t  = threadIdx.x;
  const long k0 = (long)blockIdx.y * 32;
  const long n0 = (long)blockIdx.x * 32;
  const int r  = t >> 3;
  const int c4 = (t & 7) * 4;
  float4 v = *(const float4*)&W[(k0 + r) * N + n0 + c4];
  tile[r][c4 + 0] = v.x; tile[r][c4 + 1] = v.y;
  tile[r][c4 + 2] = v.z; tile[r][c4 + 3] = v.w;
  __syncthreads();
  bf16x4 o;
#pragma unroll
  for (int i = 0; i < 4; ++i) o[i] = (__bf16)tile[c4 + i][r];
  *(bf16x4*)&Wt[(n0 + r) * K + k0 + c4] = o;
}

// ---------------------------------------------------------------------------
// LayerNorm (fp32 in) -> bf16 out. One block per row of 1024.
// ---------------------------------------------------------------------------
__global__ __launch_bounds__(256) void ln_kernel(const float* __restrict__ X,
                                                 const float* __restrict__ g,
                                                 const float* __restrict__ be,
                                                 __bf16* __restrict__ O) {
  const int t = threadIdx.x;
  const long row = blockIdx.x;
  float4 v = *(const float4*)&X[row * E + t * 4];
  float s  = v.x + v.y + v.z + v.w;
  float ss = v.x * v.x + v.y * v.y + v.z * v.z + v.w * v.w;
#pragma unroll
  for (int off = 32; off; off >>= 1) {
    s  += __shfl_down(s, off);
    ss += __shfl_down(ss, off);
  }
  __shared__ float red[8];
  const int w = t >> 6;
  if ((t & 63) == 0) { red[w] = s; red[4 + w] = ss; }
  __syncthreads();
  s  = red[0] + red[1] + red[2] + red[3];
  ss = red[4] + red[5] + red[6] + red[7];
  const float mean = s * (1.0f / E);
  const float var  = ss * (1.0f / E) - mean * mean;
  const float rstd = rsqrtf(var + 1e-5f);
  float4 gv = *(const float4*)&g[t * 4];
  float4 bv = *(const float4*)&be[t * 4];
  bf16x4 o;
  o[0] = (__bf16)((v.x - mean) * rstd * gv.x + bv.x);
  o[1] = (__bf16)((v.y - mean) * rstd * gv.y + bv.y);
  o[2] = (__bf16)((v.z - mean) * rstd * gv.z + bv.z);
  o[3] = (__bf16)((v.w - mean) * rstd * gv.w + bv.w);
  *(bf16x4*)&O[row * E + t * 4] = o;
}

// ---------------------------------------------------------------------------
// Deep-pipelined GEMM: C[M][N] = op(A[M][K] @ Bt[N][K]^T + bias) (+resid).
// BM=256, BN=128, BK=64. 512 threads = 8 waves (2 wr x 4 wc); per-wave 128x32.
// 3 LDS buffers, stage-ahead-2, counted vmcnt(6), raw s_barrier, T2 swizzle.
// ---------------------------------------------------------------------------
template <bool RELU, bool RESID, bool OUTBF, int NB>
__global__ __launch_bounds__(512, 2) void gemm8_kernel(const __bf16* __restrict__ A,
                                                       const __bf16* __restrict__ Bt,
                                                       const float* __restrict__ bias0,
                                                       const float* __restrict__ bias1,
                                                       const float* __restrict__ bias2,
                                                       const float* resid,
                                                       void* Cout,
                                                       int M, int N, int K) {
  extern __shared__ char lds[];   // 3 * (32768 A + 16384 B) = 147456 B
  const int tid  = threadIdx.x;
  const int lane = tid & 63;
  const int l15  = lane & 15;
  const int wid  = tid >> 6;
  const int wr   = wid >> 2;   // 0..1
  const int wc   = wid & 3;    // 0..3

  // XCD-aware swizzle (all grids have nwg % 8 == 0)
  const int nwg  = gridDim.x * gridDim.y;
  const int flat = blockIdx.x + gridDim.x * blockIdx.y;
  const int swz  = (flat & 7) * (nwg >> 3) + (flat >> 3);
  const int bx   = swz % gridDim.x;
  const int by   = swz / gridDim.x;
  const long brow = (long)by * 256;
  const long bcol = (long)bx * 128;

  const __bf16* Ab = A  + brow * K;
  const __bf16* Bb = Bt + bcol * K;
  const int NT = K >> 6;

  char* bA0 = lds;
  char* bA1 = lds + 49152;
  char* bA2 = lds + 98304;

  auto stageA = [&](int k0, char* base, int seg0, int seg1) {
    {
      const int r = seg0 + (tid >> 3);
      const int p = (tid & 7) ^ (r & 7);
      gload16(Ab + (long)r * K + k0 + p * 8, base + seg0 * 128 + tid * 16);
    }
    {
      const int r = seg1 + (tid >> 3);
      const int p = (tid & 7) ^ (r & 7);
      gload16(Ab + (long)r * K + k0 + p * 8, base + seg1 * 128 + tid * 16);
    }
  };
  auto stageB = [&](int k0, char* base) {
#pragma unroll
    for (int i = 0; i < 2; ++i) {
      const int c = i * 64 + (tid >> 3);
      const int p = (tid & 7) ^ (c & 7);
      gload16(Bb + (long)c * K + k0 + p * 8, base + 32768 + i * 8192 + tid * 16);
    }
  };

  f32x4 acc[8][2];
  const f32x4 z4 = {0.f, 0.f, 0.f, 0.f};
#pragma unroll
  for (int m = 0; m < 8; ++m) { acc[m][0] = z4; acc[m][1] = z4; }

  stageA(0, bA0, 0, 128);
  stageA(0, bA0, 64, 192);
  stageB(0, bA0);
  stageA(64, bA1, 0, 128);
  stageA(64, bA1, 64, 192);
  stageB(64, bA1);
  AVM(6);
  ABAR();

  for (int t = 0; t < NT; ++t) {
    const int k2 = (t + 2 < NT) ? ((t + 2) << 6) : 0;

    bf16x8 af[4][2], bfr[2][2];
#pragma unroll
    for (int m = 0; m < 4; ++m)
#pragma unroll
      for (int kk = 0; kk < 2; ++kk) {
        const int row = wr * 128 + m * 16 + l15;
        const int p   = ((kk << 2) + (lane >> 4)) ^ (row & 7);
        af[m][kk] = *(const bf16x8*)(bA0 + row * 128 + p * 16);
      }
#pragma unroll
    for (int n = 0; n < 2; ++n)
#pragma unroll
      for (int kk = 0; kk < 2; ++kk) {
        const int col = wc * 32 + n * 16 + l15;
        const int p   = ((kk << 2) + (lane >> 4)) ^ (col & 7);
        bfr[n][kk] = *(const bf16x8*)(bA0 + 32768 + col * 128 + p * 16);
      }
    stageA(k2, bA2, 0, 128);
    stageB(k2, bA2);
    ABAR();
    __builtin_amdgcn_s_setprio(1);
#pragma unroll
    for (int m = 0; m < 4; ++m)
#pragma unroll
      for (int n = 0; n < 2; ++n) {
        acc[m][n] = __builtin_amdgcn_mfma_f32_16x16x32_bf16(af[m][0], bfr[n][0], acc[m][n], 0, 0, 0);
        acc[m][n] = __builtin_amdgcn_mfma_f32_16x16x32_bf16(af[m][1], bfr[n][1], acc[m][n], 0, 0, 0);
      }
    __builtin_amdgcn_s_setprio(0);
    ABAR();

#pragma unroll
    for (int m = 0; m < 4; ++m)
#pragma unroll
      for (int kk = 0; kk < 2; ++kk) {
        const int row = wr * 128 + (m + 4) * 16 + l15;
        const int p   = ((kk << 2) + (lane >> 4)) ^ (row & 7);
        af[m][kk] = *(const bf16x8*)(bA0 + row * 128 + p * 16);
      }
    stageA(k2, bA2, 64, 192);
    ABAR();
    __builtin_amdgcn_s_setprio(1);
#pragma unroll
    for (int m = 0; m < 4; ++m)
#pragma unroll
      for (int n = 0; n < 2; ++n) {
        acc[m + 4][n] = __builtin_amdgcn_mfma_f32_16x16x32_bf16(af[m][0], bfr[n][0], acc[m + 4][n], 0, 0, 0);
        acc[m + 4][n] = __builtin_amdgcn_mfma_f32_16x16x32_bf16(af[m][1], bfr[n][1], acc[m + 4][n], 0, 0, 0);
      }
    __builtin_amdgcn_s_setprio(0);
    AVM(6);
    ABAR();

    char* tmp = bA0; bA0 = bA1; bA1 = bA2; bA2 = tmp;
  }
  AVM(0);

#pragma unroll
  for (int m = 0; m < 8; ++m) {
#pragma unroll
    for (int n = 0; n < 2; ++n) {
      const long col = bcol + wc * 32 + n * 16 + l15;
      float bb;
      if (NB == 3) {
        const float* bp = (col < 1024) ? bias0 : ((col < 2048) ? bias1 : bias2);
        bb = bp[col & 1023];
      } else {
        bb = bias0[col];
      }
#pragma unroll
      for (int j = 0; j < 4; ++j) {
        const long row = brow + wr * 128 + m * 16 + (lane >> 4) * 4 + j;
        float val = acc[m][n][j] + bb;
        if (RELU) val = fmaxf(val, 0.f);
        const long idx = row * N + col;
        if (RESID) val += resid[idx];
        if (OUTBF) ((__bf16*)Cout)[idx] = (__bf16)val;
        else       ((float*)Cout)[idx]  = val;
      }
    }
  }
}

// ---------------------------------------------------------------------------
// Flash attention, swapped-operand 32x32 structure (m214-style):
// block = 128 q rows of one (b,h); 4 waves x 32 q; KVBLK=64 double-buffered.
// QK^T swapped: s = mfma(K, Q) -> lane holds P[q=lane&31][64 keys] in 32 f32.
// In-register softmax (per-lane scalar m/l), defer-max THR=8 (raw 64).
// P->bf16 A-frags via v_cvt_pk_bf16_f32 + v_permlane32_swap_b32 (T12).
// PV swapped: ctx = mfma(Vt, P) -> O^T, cols = q = lane&31.
// K staged via global_load_lds (pre-swizzled source); V via reg->LDS transpose.
// Swizzles: Qs/Ks piece ^= (row&7); Vt piece ^= (d>>3) with piece=(key>>3).
// ---------------------------------------------------------------------------
__global__ __launch_bounds__(256, 3) void attn_kernel(const __bf16* __restrict__ QKV,
                                                      __bf16* __restrict__ Og) {
  __shared__ __align__(16) __bf16 Qs[128 * 64];    // 16KB [qrow][d]
  __shared__ __align__(16) __bf16 Ks[2][64 * 64];  // 2x8KB [key][d]
  __shared__ __align__(16) __bf16 Vt[2][64 * 64];  // 2x8KB [d][key]

  const int QSTR = 3072;
  const int t    = threadIdx.x;
  const int lane = t & 63;
  const int w    = t >> 6;       // wave 0..3
  const int l31  = lane & 31;
  const int h    = lane >> 5;    // half 0/1
  const int b    = blockIdx.y >> 4;
  const int hh   = blockIdx.y & 15;
  const long row0 = (long)b * 1024 + (long)blockIdx.x * 128;
  const long kvrow0 = (long)b * 1024;
  const int colQ = hh * 64;
  const int colK = colQ + 1024;
  const int colV = colQ + 2048;

  // ---- prologue: stage Q (once), K[0], V[0] ----
#pragma unroll
  for (int j = 0; j < 4; ++j) {
    const int c = j * 256 + t;
    const int r = c >> 3;
    const int p = (c & 7) ^ (r & 7);
    gload16(QKV + (row0 + r) * QSTR + colQ + p * 8, (char*)Qs + c * 16);
  }
#pragma unroll
  for (int j = 0; j < 2; ++j) {
    const int c = j * 256 + t;
    const int r = c >> 3;
    const int p = (c & 7) ^ (r & 7);
    gload16(QKV + (kvrow0 + r) * QSTR + colK + p * 8, (char*)Ks[0] + c * 16);
  }
  bf16x8 vv[2];
#pragma unroll
  for (int j = 0; j < 2; ++j) {
    const int c = j * 256 + t;
    const int key = c >> 3, dc = c & 7;
    vv[j] = *(const bf16x8*)(QKV + (kvrow0 + key) * QSTR + colV + dc * 8);
  }
  AVM(0);
#pragma unroll
  for (int j = 0; j < 2; ++j) {
    const int c = j * 256 + t;
    const int key = c >> 3, dc = c & 7;
#pragma unroll
    for (int e = 0; e < 8; ++e) {
      const int d = dc * 8 + e;
      *(__bf16*)((char*)Vt[0] + d * 128 + (((key >> 3) ^ dc) * 16) + (key & 7) * 2) = vv[j][e];
    }
  }
  __syncthreads();

  // hoist Q fragments (B-operand: col=q=l31, k-chunk = kk*16 + h*8)
  bf16x8 bq[4];
  {
    const int qrow = w * 32 + l31;
#pragma unroll
    for (int kk = 0; kk < 4; ++kk) {
      const int p = (kk * 2 + h) ^ (qrow & 7);
      bq[kk] = *(const bf16x8*)((const char*)Qs + qrow * 128 + p * 16);
    }
  }

  f32x16 ctx0, ctx1;
#pragma unroll
  for (int r = 0; r < 16; ++r) { ctx0[r] = 0.f; ctx1[r] = 0.f; }
  float m = -INFINITY, l = 0.f;

  for (int kb = 0; kb < 16; ++kb) {
    const int cur = kb & 1, nxt = cur ^ 1;
    const int kb1 = (kb + 1 < 16) ? kb + 1 : kb;
    const long kr1 = kvrow0 + kb1 * 64;

    // prefetch next tile: V reg-loads first, then K global->LDS
#pragma unroll
    for (int j = 0; j < 2; ++j) {
      const int c = j * 256 + t;
      const int key = c >> 3, dc = c & 7;
      vv[j] = *(const bf16x8*)(QKV + (kr1 + key) * QSTR + colV + dc * 8);
    }
#pragma unroll
    for (int j = 0; j < 2; ++j) {
      const int c = j * 256 + t;
      const int r = c >> 3;
      const int p = (c & 7) ^ (r & 7);
      gload16(QKV + (kr1 + r) * QSTR + colK + p * 8, (char*)Ks[nxt] + c * 16);
    }

    // ---- QK^T swapped: A=K rows(keys), B=Q cols(q) ----
    f32x16 s0, s1;
#pragma unroll
    for (int r = 0; r < 16; ++r) { s0[r] = 0.f; s1[r] = 0.f; }
    __builtin_amdgcn_s_setprio(1);
#pragma unroll
    for (int kk = 0; kk < 4; ++kk) {
      const int pce = kk * 2 + h;
      const int p0i = pce ^ (l31 & 7);
      bf16x8 ak0 = *(const bf16x8*)((const char*)Ks[cur] + l31 * 128 + p0i * 16);
      bf16x8 ak1 = *(const bf16x8*)((const char*)Ks[cur] + (32 + l31) * 128 + p0i * 16);
      s0 = __builtin_amdgcn_mfma_f32_32x32x16_bf16(ak0, bq[kk], s0, 0, 0, 0);
      s1 = __builtin_amdgcn_mfma_f32_32x32x16_bf16(ak1, bq[kk], s1, 0, 0, 0);
    }
    __builtin_amdgcn_s_setprio(0);

    // ---- in-register online softmax (raw units; scale 1/8 folded into exp) ----
    float mx = s0[0];
#pragma unroll
    for (int r = 1; r < 16; ++r) mx = fmaxf(mx, s0[r]);
#pragma unroll
    for (int r = 0; r < 16; ++r) mx = fmaxf(mx, s1[r]);
    mx = fmaxf(mx, __shfl_xor(mx, 32));

    if (!__all(mx - m <= 64.f)) {   // defer-max THR = 8 (x8 raw)
      const float mn = fmaxf(m, mx);
      const float corr = __expf((m - mn) * 0.125f);
      l *= corr;
#pragma unroll
      for (int r = 0; r < 16; ++r) { ctx0[r] *= corr; ctx1[r] *= corr; }
      m = mn;
    }
    f32x16 p0, p1;
    float rs = 0.f;
#pragma unroll
    for (int r = 0; r < 16; ++r) { p0[r] = __expf((s0[r] - m) * 0.125f); rs += p0[r]; }
#pragma unroll
    for (int r = 0; r < 16; ++r) { p1[r] = __expf((s1[r] - m) * 0.125f); rs += p1[r]; }
    rs += __shfl_xor(rs, 32);
    l += rs;

    // ---- write V[t+1] transpose into Vt[nxt] ----
    AVM(2);
#pragma unroll
    for (int j = 0; j < 2; ++j) {
      const int c = j * 256 + t;
      const int key = c >> 3, dc = c & 7;
#pragma unroll
      for (int e = 0; e < 8; ++e) {
        const int d = dc * 8 + e;
        *(__bf16*)((char*)Vt[nxt] + d * 128 + (((key >> 3) ^ dc) * 16) + (key & 7) * 2) = vv[j][e];
      }
    }

    // ---- build PV B-operand frags: pa[ks][e] = P[k=ks*16+h*8+e][q] ----
    bf16x8 paf[4];
#pragma unroll
    for (int ks = 0; ks < 4; ++ks) {
      const int base = (ks & 1) * 8;
      unsigned a0, a1, b0, b1;
      if (ks < 2) {
        CVTPK(a0, p0[base + 0], p0[base + 1]);
        CVTPK(b0, p0[base + 4], p0[base + 5]);
        CVTPK(a1, p0[base + 2], p0[base + 3]);
        CVTPK(b1, p0[base + 6], p0[base + 7]);
      } else {
        CVTPK(a0, p1[base + 0], p1[base + 1]);
        CVTPK(b0, p1[base + 4], p1[base + 5]);
        CVTPK(a1, p1[base + 2], p1[base + 3]);
        CVTPK(b1, p1[base + 6], p1[base + 7]);
      }
      PLSWAP(a0, b0);   // a0 -> word0, b0 -> word2
      PLSWAP(a1, b1);   // a1 -> word1, b1 -> word3
      u32x4 wv4; wv4[0] = a0; wv4[1] = a1; wv4[2] = b0; wv4[3] = b1;
      paf[ks] = __builtin_bit_cast(bf16x8, wv4);
    }

    // ---- PV swapped: ctx(O^T) += mfma(A=Vt rows(d), B=P cols(q)) ----
    __builtin_amdgcn_s_setprio(1);
#pragma unroll
    for (int ks = 0; ks < 4; ++ks) {
      const int pce = ks * 2 + h;
      bf16x8 av0 = *(const bf16x8*)((const char*)Vt[cur] + l31 * 128 + ((pce ^ (l31 >> 3)) * 16));
      bf16x8 av1 = *(const bf16x8*)((const char*)Vt[cur] + (32 + l31) * 128 + ((pce ^ (4 + (l31 >> 3))) * 16));
      ctx0 = __builtin_amdgcn_mfma_f32_32x32x16_bf16(av0, paf[ks], ctx0, 0, 0, 0);
      ctx1 = __builtin_amdgcn_mfma_f32_32x32x16_bf16(av1, paf[ks], ctx1, 0, 0, 0);
    }
    __builtin_amdgcn_s_setprio(0);

    __syncthreads();   // drains vmcnt (K[t+1] landed) + publishes Vt[nxt]
  }

  // ---- epilogue: O[q][d] = ctx^T / l ; d = (r&3)+8*(r>>2)+4h+32f ----
  const float inv = 1.0f / l;
  const long orow = row0 + w * 32 + l31;
#pragma unroll
  for (int f = 0; f < 2; ++f)
#pragma unroll
    for (int tq = 0; tq < 4; ++tq) {
      bf16x4 o;
#pragma unroll
      for (int e = 0; e < 4; ++e) {
        const float v = (f ? ctx1[tq * 4 + e] : ctx0[tq * 4 + e]) * inv;
        o[e] = (__bf16)v;
      }
      const int col = colQ + f * 32 + tq * 8 + h * 4;
      *(bf16x4*)&Og[orow * E + col] = o;
    }
}

// ---------------------------------------------------------------------------
extern "C" void kernel_launch(void* const* d_in, const int* in_sizes, int n_in,
                              void* d_out, int out_size, void* d_ws, size_t ws_size,
                              hipStream_t stream) {
  const float* x     = (const float*)d_in[0];
  const float* ln1g  = (const float*)d_in[1];
  const float* ln1b  = (const float*)d_in[2];
  const float* ln2g  = (const float*)d_in[3];
  const float* ln2b  = (const float*)d_in[4];
  const float* wq    = (const float*)d_in[5];
  const float* bq    = (const float*)d_in[6];
  const float* wk    = (const float*)d_in[7];
  const float* bk    = (const float*)d_in[8];
  const float* wv    = (const float*)d_in[9];
  const float* bv    = (const float*)d_in[10];
  const float* wo    = (const float*)d_in[11];
  const float* bo    = (const float*)d_in[12];
  const float* w1    = (const float*)d_in[13];
  const float* b1    = (const float*)d_in[14];
  const float* w2    = (const float*)d_in[15];
  const float* b2    = (const float*)d_in[16];
  float* out = (float*)d_out;

  char* ws = (char*)d_ws;
  const size_t MB = 1024 * 1024;
  __bf16* Wqkv = (__bf16*)(ws + 0 * MB);    // [3072][1024] bf16, 6MB (q|k|v rows)
  __bf16* Wot  = (__bf16*)(ws + 6 * MB);    // [1024][1024] 2MB
  __bf16* W1t  = (__bf16*)(ws + 8 * MB);    // [4096][1024] 8MB
  __bf16* W2t  = (__bf16*)(ws + 16 * MB);   // [1024][4096] 8MB
  __bf16* h    = (__bf16*)(ws + 24 * MB);   // [8192][1024] 16MB
  __bf16* qkv  = (__bf16*)(ws + 40 * MB);   // [8192][3072] 48MB
  __bf16* ctx  = (__bf16*)(ws + 88 * MB);   // [8192][1024] 16MB (total 104MB)
  __bf16* ff1  = (__bf16*)(ws + 40 * MB);   // [8192][4096] 64MB, aliases qkv (dead)

  const dim3 blk(256);
  const dim3 blk512(512);
  const size_t GLDS = 147456;               // 3 * (32KB A + 16KB B)

  // weights -> bf16 transposed [N][K]; q/k/v stacked into Wqkv
  wconv_kernel<<<dim3(E / 32, E / 32), blk, 0, stream>>>(wq, Wqkv, E, E);
  wconv_kernel<<<dim3(E / 32, E / 32), blk, 0, stream>>>(wk, Wqkv + 1024 * 1024, E, E);
  wconv_kernel<<<dim3(E / 32, E / 32), blk, 0, stream>>>(wv, Wqkv + 2048 * 1024, E, E);
  wconv_kernel<<<dim3(E / 32, E / 32), blk, 0, stream>>>(wo, Wot, E, E);
  wconv_kernel<<<dim3(HID / 32, E / 32), blk, 0, stream>>>(w1, W1t, E, HID);
  wconv_kernel<<<dim3(E / 32, HID / 32), blk, 0, stream>>>(w2, W2t, HID, E);

  // LN1
  ln_kernel<<<TOK, blk, 0, stream>>>(x, ln1g, ln1b, h);

  // fused QKV projection: [8192][3072]   (grid 24x32 = 768 blocks)
  gemm8_kernel<false, false, true, 3><<<dim3(3072 / 128, TOK / 256), blk512, GLDS, stream>>>(
      h, Wqkv, bq, bk, bv, nullptr, qkv, TOK, 3072, E);

  // attention: 8 q-blocks of 128 rows x 128 (b,h)
  attn_kernel<<<dim3(8, 128), blk, 0, stream>>>(qkv, ctx);

  // O projection + residual(x) -> d_out (fp32)   (grid 8x32 = 256 blocks)
  gemm8_kernel<false, true, false, 1><<<dim3(E / 128, TOK / 256), blk512, GLDS, stream>>>(
      ctx, Wot, bo, nullptr, nullptr, x, out, TOK, E, E);

  // LN2 on d_out
  ln_kernel<<<TOK, blk, 0, stream>>>(out, ln2g, ln2b, h);

  // FF1 with ReLU -> ff1 (bf16)   (grid 32x32 = 1024 blocks)
  gemm8_kernel<true, false, true, 1><<<dim3(HID / 128, TOK / 256), blk512, GLDS, stream>>>(
      h, W1t, b1, nullptr, nullptr, nullptr, ff1, TOK, HID, E);

  // FF2 + residual(d_out) -> d_out (in-place, element-wise safe)
  gemm8_kernel<false, true, false, 1><<<dim3(E / 128, TOK / 256), blk512, GLDS, stream>>>(
      ff1, W2t, b2, nullptr, nullptr, out, out, TOK, E, HID);
}

// Round 6
// 353.466 us; speedup vs baseline: 1.7234x; 1.0506x over previous
//
#include <hip/hip_runtime.h>
#include <hip/hip_bf16.h>

typedef __attribute__((ext_vector_type(4))) float f32x4;
typedef __attribute__((ext_vector_type(16))) float f32x16;
typedef __attribute__((ext_vector_type(8))) __bf16 bf16x8;
typedef __attribute__((ext_vector_type(4))) __bf16 bf16x4;
typedef __attribute__((ext_vector_type(4))) unsigned int u32x4;

static constexpr int E    = 1024;
static constexpr int TOK  = 8192;   // 8 * 1024 tokens
static constexpr int HID  = 4096;

#define DEVINL __device__ __forceinline__

// async global->LDS, 16B per lane. LDS dest must be lane-linear (wave base + lane*16).
DEVINL void gload16(const void* g, void* l) {
  __builtin_amdgcn_global_load_lds((__attribute__((address_space(1))) void*)g,
                                   (__attribute__((address_space(3))) void*)l, 16, 0, 0);
}

#define ABAR()  asm volatile("s_barrier" ::: "memory")
#define AVM(n)  asm volatile("s_waitcnt vmcnt(" #n ")" ::: "memory")
#define CVTPK(dst, lo, hi) asm("v_cvt_pk_bf16_f32 %0, %1, %2" : "=v"(dst) : "v"(lo), "v"(hi))
#define PLSWAP(a, b) asm("v_permlane32_swap_b32 %0, %1" : "+v"(a), "+v"(b))

template <int N> DEVINL void avm() {
  if constexpr (N == 0)      asm volatile("s_waitcnt vmcnt(0)" ::: "memory");
  else if constexpr (N == 2) asm volatile("s_waitcnt vmcnt(2)" ::: "memory");
  else if constexpr (N == 3) asm volatile("s_waitcnt vmcnt(3)" ::: "memory");
  else if constexpr (N == 4) asm volatile("s_waitcnt vmcnt(4)" ::: "memory");
  else                       asm volatile("s_waitcnt vmcnt(6)" ::: "memory");
}

// ---------------------------------------------------------------------------
// Weight convert + transpose: W[K][N] f32 -> Wt[N][K] bf16 (32x32 LDS tiles)
// ---------------------------------------------------------------------------
__global__ __launch_bounds__(256) void wconv_kernel(const float* __restrict__ W,
                                                    __bf16* __restrict__ Wt,
                                                    int K, int N) {
  __shared__ float tile[32][33];
  const int t  = threadIdx.x;
  const long k0 = (long)blockIdx.y * 32;
  const long n0 = (long)blockIdx.x * 32;
  const int r  = t >> 3;
  const int c4 = (t & 7) * 4;
  float4 v = *(const float4*)&W[(k0 + r) * N + n0 + c4];
  tile[r][c4 + 0] = v.x; tile[r][c4 + 1] = v.y;
  tile[r][c4 + 2] = v.z; tile[r][c4 + 3] = v.w;
  __syncthreads();
  bf16x4 o;
#pragma unroll
  for (int i = 0; i < 4; ++i) o[i] = (__bf16)tile[c4 + i][r];
  *(bf16x4*)&Wt[(n0 + r) * K + k0 + c4] = o;
}

// ---------------------------------------------------------------------------
// LayerNorm (fp32 in) -> bf16 out. One block per row of 1024.
// ---------------------------------------------------------------------------
__global__ __launch_bounds__(256) void ln_kernel(const float* __restrict__ X,
                                                 const float* __restrict__ g,
                                                 const float* __restrict__ be,
                                                 __bf16* __restrict__ O) {
  const int t = threadIdx.x;
  const long row = blockIdx.x;
  float4 v = *(const float4*)&X[row * E + t * 4];
  float s  = v.x + v.y + v.z + v.w;
  float ss = v.x * v.x + v.y * v.y + v.z * v.z + v.w * v.w;
#pragma unroll
  for (int off = 32; off; off >>= 1) {
    s  += __shfl_down(s, off);
    ss += __shfl_down(ss, off);
  }
  __shared__ float red[8];
  const int w = t >> 6;
  if ((t & 63) == 0) { red[w] = s; red[4 + w] = ss; }
  __syncthreads();
  s  = red[0] + red[1] + red[2] + red[3];
  ss = red[4] + red[5] + red[6] + red[7];
  const float mean = s * (1.0f / E);
  const float var  = ss * (1.0f / E) - mean * mean;
  const float rstd = rsqrtf(var + 1e-5f);
  float4 gv = *(const float4*)&g[t * 4];
  float4 bv = *(const float4*)&be[t * 4];
  bf16x4 o;
  o[0] = (__bf16)((v.x - mean) * rstd * gv.x + bv.x);
  o[1] = (__bf16)((v.y - mean) * rstd * gv.y + bv.y);
  o[2] = (__bf16)((v.z - mean) * rstd * gv.z + bv.z);
  o[3] = (__bf16)((v.w - mean) * rstd * gv.w + bv.w);
  *(bf16x4*)&O[row * E + t * 4] = o;
}

// ---------------------------------------------------------------------------
// 4-phase counted-vmcnt GEMM: C[M][N] = op(A[M][K] @ Bt[N][K]^T + bias)(+resid)
// BM_ in {256,128}, BN=256, BK=64. 512 threads = 8 waves (2 wr x 4 wc).
// Per-wave output: (BM_/2) x 64, row = m*32+wr*16 (interleaved), col = n*64+wc*16.
// LDS layout: [A0 | A1 | B0 | B1], A buf = BM_*128 B, B buf = 32KB.
// Per K-tile, 4 phases; each: {vmcnt(V); s_barrier; ds_read quadrant;
// issue 1 half-tile stage of t+1; MFMA quadrant}. Stage order A-lo,B-lo,B-hi,A-hi.
// vmcnt ledger (per thread): BM=256 waits 4/4/4; BM=128 waits 3/2/3. Never 0 in loop.
// T2 XOR swizzle via pre-swizzled global source, swizzled ds_read (piece ^= row&7).
// ---------------------------------------------------------------------------
template <int BM_, bool RELU, bool RESID, bool OUTBF, int NB>
__global__ __launch_bounds__(512, 2) void gemm256_kernel(const __bf16* __restrict__ A,
                                                         const __bf16* __restrict__ Bt,
                                                         const float* __restrict__ bias0,
                                                         const float* __restrict__ bias1,
                                                         const float* __restrict__ bias2,
                                                         const float* resid,
                                                         void* Cout,
                                                         int M, int N, int K) {
  extern __shared__ char lds[];
  constexpr int MH   = BM_ / 64;        // m-frags per half (4 or 2)
  constexpr int ASZ  = BM_ * 128;       // A buffer bytes (BM_*64*2B)
  constexpr int BOFF = 2 * ASZ;         // B buffers base
  constexpr int V1   = (BM_ == 256) ? 4 : 3;
  constexpr int V2   = (BM_ == 256) ? 4 : 2;
  constexpr int V3   = (BM_ == 256) ? 4 : 3;

  const int tid  = threadIdx.x;
  const int lane = tid & 63;
  const int l15  = lane & 15;
  const int wid  = tid >> 6;
  const int wr   = wid >> 2;   // 0..1
  const int wc   = wid & 3;    // 0..3

  // XCD-aware swizzle (all grids have nwg % 8 == 0)
  const int nwg  = gridDim.x * gridDim.y;
  const int flat = blockIdx.x + gridDim.x * blockIdx.y;
  const int swz  = (flat & 7) * (nwg >> 3) + (flat >> 3);
  const int bx   = swz % gridDim.x;
  const int by   = swz / gridDim.x;
  const long brow = (long)by * BM_;
  const long bcol = (long)bx * 256;

  const __bf16* Ab = A  + brow * K;
  const __bf16* Bb = Bt + bcol * K;
  const int NT = K >> 6;

  // stage one A half-tile (BM_/2 rows x 64 k) into dst (linear, pre-swizzled src)
  auto stageAhalf = [&](int k0, int rbase, char* dst) {
#pragma unroll
    for (int i = 0; i < BM_ / 128; ++i) {
      const int c = i * 512 + tid;
      const int r = c >> 3;
      const int p = (c & 7) ^ (r & 7);
      gload16(Ab + (long)(rbase + r) * K + k0 + p * 8, dst + c * 16);
    }
  };
  // stage one B half-tile (128 cols x 64 k)
  auto stageBhalf = [&](int k0, int cbase, char* dst) {
#pragma unroll
    for (int i = 0; i < 2; ++i) {
      const int c = i * 512 + tid;
      const int r = c >> 3;
      const int p = (c & 7) ^ (r & 7);
      gload16(Bb + (long)(cbase + r) * K + k0 + p * 8, dst + c * 16);
    }
  };

  f32x4 acc[2 * MH][4];
  const f32x4 z4 = {0.f, 0.f, 0.f, 0.f};
#pragma unroll
  for (int m = 0; m < 2 * MH; ++m)
#pragma unroll
    for (int n = 0; n < 4; ++n) acc[m][n] = z4;

  bf16x8 af[MH][2], bfr[4][2];

  auto readA = [&](const char* Ac, int mbase) {
#pragma unroll
    for (int mm = 0; mm < MH; ++mm)
#pragma unroll
      for (int kk = 0; kk < 2; ++kk) {
        const int row = (mbase + mm) * 32 + wr * 16 + l15;
        const int p   = ((kk << 2) + (lane >> 4)) ^ (row & 7);
        af[mm][kk] = *(const bf16x8*)(Ac + row * 128 + p * 16);
      }
  };
  auto readB = [&](const char* Bc, int nbase) {
#pragma unroll
    for (int nn = 0; nn < 2; ++nn)
#pragma unroll
      for (int kk = 0; kk < 2; ++kk) {
        const int col = (nbase + nn) * 64 + wc * 16 + l15;
        const int p   = ((kk << 2) + (lane >> 4)) ^ (col & 7);
        bfr[nbase + nn][kk] = *(const bf16x8*)(Bc + col * 128 + p * 16);
      }
  };
  auto domfma = [&](int mb, int nb) {
    __builtin_amdgcn_s_setprio(1);
#pragma unroll
    for (int mm = 0; mm < MH; ++mm)
#pragma unroll
      for (int nn = 0; nn < 2; ++nn) {
        f32x4 a = acc[mb + mm][nb + nn];
        a = __builtin_amdgcn_mfma_f32_16x16x32_bf16(af[mm][0], bfr[nb + nn][0], a, 0, 0, 0);
        a = __builtin_amdgcn_mfma_f32_16x16x32_bf16(af[mm][1], bfr[nb + nn][1], a, 0, 0, 0);
        acc[mb + mm][nb + nn] = a;
      }
    __builtin_amdgcn_s_setprio(0);
  };

  // ---- prologue: stage tile 0, order A-lo, B-lo, B-hi, A-hi ----
  stageAhalf(0, 0, lds);
  stageBhalf(0, 0, lds + BOFF);
  stageBhalf(0, 128, lds + BOFF + 16384);
  stageAhalf(0, BM_ / 2, lds + ASZ / 2);

  for (int t = 0; t < NT; ++t) {
    const int cur = t & 1;
    const int nxt = cur ^ 1;
    char* Ac = lds + cur * ASZ;
    char* Bc = lds + BOFF + cur * 32768;
    char* An = lds + nxt * ASZ;
    char* Bn = lds + BOFF + nxt * 32768;
    const int kt = (t + 1 < NT) ? ((t + 1) << 6) : 0;  // tail stages dummy k=0

    // ph1: needs A-lo(t), B-lo(t)
    avm<V1>(); ABAR();
    readA(Ac, 0);
    readB(Bc, 0);
    stageAhalf(kt, 0, An);
    domfma(0, 0);

    // ph2: needs B-hi(t)
    avm<V2>(); ABAR();
    readB(Bc, 2);
    stageBhalf(kt, 0, Bn);
    domfma(0, 2);

    // ph3: needs A-hi(t)
    avm<V3>(); ABAR();
    readA(Ac, MH);
    stageBhalf(kt, 128, Bn + 16384);
    domfma(MH, 0);

    // ph4: register-only MFMA; stage A-hi(t+1)
    stageAhalf(kt, BM_ / 2, An + ASZ / 2);
    domfma(MH, 2);
  }
  avm<0>();  // drain dummy stages

  // ---- epilogue. D layout: col=lane&15, row=(lane>>4)*4+j within frag ----
#pragma unroll
  for (int m = 0; m < 2 * MH; ++m) {
#pragma unroll
    for (int n = 0; n < 4; ++n) {
      const long col = bcol + n * 64 + wc * 16 + l15;
      float bb;
      if (NB == 3) {
        const float* bp = (col < 1024) ? bias0 : ((col < 2048) ? bias1 : bias2);
        bb = bp[col & 1023];
      } else {
        bb = bias0[col];
      }
#pragma unroll
      for (int j = 0; j < 4; ++j) {
        const long row = brow + m * 32 + wr * 16 + (lane >> 4) * 4 + j;
        float val = acc[m][n][j] + bb;
        if (RELU) val = fmaxf(val, 0.f);
        const long idx = row * N + col;
        if (RESID) val += resid[idx];
        if (OUTBF) ((__bf16*)Cout)[idx] = (__bf16)val;
        else       ((float*)Cout)[idx]  = val;
      }
    }
  }
}

// ---------------------------------------------------------------------------
// Flash attention, swapped-operand 32x32 structure (m214-style). Unchanged R4.
// ---------------------------------------------------------------------------
__global__ __launch_bounds__(256, 3) void attn_kernel(const __bf16* __restrict__ QKV,
                                                      __bf16* __restrict__ Og) {
  __shared__ __align__(16) __bf16 Qs[128 * 64];    // 16KB [qrow][d]
  __shared__ __align__(16) __bf16 Ks[2][64 * 64];  // 2x8KB [key][d]
  __shared__ __align__(16) __bf16 Vt[2][64 * 64];  // 2x8KB [d][key]

  const int QSTR = 3072;
  const int t    = threadIdx.x;
  const int lane = t & 63;
  const int w    = t >> 6;       // wave 0..3
  const int l31  = lane & 31;
  const int h    = lane >> 5;    // half 0/1
  const int b    = blockIdx.y >> 4;
  const int hh   = blockIdx.y & 15;
  const long row0 = (long)b * 1024 + (long)blockIdx.x * 128;
  const long kvrow0 = (long)b * 1024;
  const int colQ = hh * 64;
  const int colK = colQ + 1024;
  const int colV = colQ + 2048;

  // ---- prologue: stage Q (once), K[0], V[0] ----
#pragma unroll
  for (int j = 0; j < 4; ++j) {
    const int c = j * 256 + t;
    const int r = c >> 3;
    const int p = (c & 7) ^ (r & 7);
    gload16(QKV + (row0 + r) * QSTR + colQ + p * 8, (char*)Qs + c * 16);
  }
#pragma unroll
  for (int j = 0; j < 2; ++j) {
    const int c = j * 256 + t;
    const int r = c >> 3;
    const int p = (c & 7) ^ (r & 7);
    gload16(QKV + (kvrow0 + r) * QSTR + colK + p * 8, (char*)Ks[0] + c * 16);
  }
  bf16x8 vv[2];
#pragma unroll
  for (int j = 0; j < 2; ++j) {
    const int c = j * 256 + t;
    const int key = c >> 3, dc = c & 7;
    vv[j] = *(const bf16x8*)(QKV + (kvrow0 + key) * QSTR + colV + dc * 8);
  }
  AVM(0);
#pragma unroll
  for (int j = 0; j < 2; ++j) {
    const int c = j * 256 + t;
    const int key = c >> 3, dc = c & 7;
#pragma unroll
    for (int e = 0; e < 8; ++e) {
      const int d = dc * 8 + e;
      *(__bf16*)((char*)Vt[0] + d * 128 + (((key >> 3) ^ dc) * 16) + (key & 7) * 2) = vv[j][e];
    }
  }
  __syncthreads();

  // hoist Q fragments (B-operand: col=q=l31, k-chunk = kk*16 + h*8)
  bf16x8 bq[4];
  {
    const int qrow = w * 32 + l31;
#pragma unroll
    for (int kk = 0; kk < 4; ++kk) {
      const int p = (kk * 2 + h) ^ (qrow & 7);
      bq[kk] = *(const bf16x8*)((const char*)Qs + qrow * 128 + p * 16);
    }
  }

  f32x16 ctx0, ctx1;
#pragma unroll
  for (int r = 0; r < 16; ++r) { ctx0[r] = 0.f; ctx1[r] = 0.f; }
  float m = -INFINITY, l = 0.f;

  for (int kb = 0; kb < 16; ++kb) {
    const int cur = kb & 1, nxt = cur ^ 1;
    const int kb1 = (kb + 1 < 16) ? kb + 1 : kb;
    const long kr1 = kvrow0 + kb1 * 64;

    // prefetch next tile: V reg-loads first, then K global->LDS
#pragma unroll
    for (int j = 0; j < 2; ++j) {
      const int c = j * 256 + t;
      const int key = c >> 3, dc = c & 7;
      vv[j] = *(const bf16x8*)(QKV + (kr1 + key) * QSTR + colV + dc * 8);
    }
#pragma unroll
    for (int j = 0; j < 2; ++j) {
      const int c = j * 256 + t;
      const int r = c >> 3;
      const int p = (c & 7) ^ (r & 7);
      gload16(QKV + (kr1 + r) * QSTR + colK + p * 8, (char*)Ks[nxt] + c * 16);
    }

    // ---- QK^T swapped: A=K rows(keys), B=Q cols(q) ----
    f32x16 s0, s1;
#pragma unroll
    for (int r = 0; r < 16; ++r) { s0[r] = 0.f; s1[r] = 0.f; }
    __builtin_amdgcn_s_setprio(1);
#pragma unroll
    for (int kk = 0; kk < 4; ++kk) {
      const int pce = kk * 2 + h;
      const int p0i = pce ^ (l31 & 7);
      bf16x8 ak0 = *(const bf16x8*)((const char*)Ks[cur] + l31 * 128 + p0i * 16);
      bf16x8 ak1 = *(const bf16x8*)((const char*)Ks[cur] + (32 + l31) * 128 + p0i * 16);
      s0 = __builtin_amdgcn_mfma_f32_32x32x16_bf16(ak0, bq[kk], s0, 0, 0, 0);
      s1 = __builtin_amdgcn_mfma_f32_32x32x16_bf16(ak1, bq[kk], s1, 0, 0, 0);
    }
    __builtin_amdgcn_s_setprio(0);

    // ---- in-register online softmax (raw units; scale 1/8 folded into exp) ----
    float mx = s0[0];
#pragma unroll
    for (int r = 1; r < 16; ++r) mx = fmaxf(mx, s0[r]);
#pragma unroll
    for (int r = 0; r < 16; ++r) mx = fmaxf(mx, s1[r]);
    mx = fmaxf(mx, __shfl_xor(mx, 32));

    if (!__all(mx - m <= 64.f)) {   // defer-max THR = 8 (x8 raw)
      const float mn = fmaxf(m, mx);
      const float corr = __expf((m - mn) * 0.125f);
      l *= corr;
#pragma unroll
      for (int r = 0; r < 16; ++r) { ctx0[r] *= corr; ctx1[r] *= corr; }
      m = mn;
    }
    f32x16 p0, p1;
    float rs = 0.f;
#pragma unroll
    for (int r = 0; r < 16; ++r) { p0[r] = __expf((s0[r] - m) * 0.125f); rs += p0[r]; }
#pragma unroll
    for (int r = 0; r < 16; ++r) { p1[r] = __expf((s1[r] - m) * 0.125f); rs += p1[r]; }
    rs += __shfl_xor(rs, 32);
    l += rs;

    // ---- write V[t+1] transpose into Vt[nxt] ----
    AVM(2);
#pragma unroll
    for (int j = 0; j < 2; ++j) {
      const int c = j * 256 + t;
      const int key = c >> 3, dc = c & 7;
#pragma unroll
      for (int e = 0; e < 8; ++e) {
        const int d = dc * 8 + e;
        *(__bf16*)((char*)Vt[nxt] + d * 128 + (((key >> 3) ^ dc) * 16) + (key & 7) * 2) = vv[j][e];
      }
    }

    // ---- build PV B-operand frags: pa[ks][e] = P[k=ks*16+h*8+e][q] ----
    bf16x8 paf[4];
#pragma unroll
    for (int ks = 0; ks < 4; ++ks) {
      const int base = (ks & 1) * 8;
      unsigned a0, a1, b0, b1;
      if (ks < 2) {
        CVTPK(a0, p0[base + 0], p0[base + 1]);
        CVTPK(b0, p0[base + 4], p0[base + 5]);
        CVTPK(a1, p0[base + 2], p0[base + 3]);
        CVTPK(b1, p0[base + 6], p0[base + 7]);
      } else {
        CVTPK(a0, p1[base + 0], p1[base + 1]);
        CVTPK(b0, p1[base + 4], p1[base + 5]);
        CVTPK(a1, p1[base + 2], p1[base + 3]);
        CVTPK(b1, p1[base + 6], p1[base + 7]);
      }
      PLSWAP(a0, b0);   // a0 -> word0, b0 -> word2
      PLSWAP(a1, b1);   // a1 -> word1, b1 -> word3
      u32x4 wv4; wv4[0] = a0; wv4[1] = a1; wv4[2] = b0; wv4[3] = b1;
      paf[ks] = __builtin_bit_cast(bf16x8, wv4);
    }

    // ---- PV swapped: ctx(O^T) += mfma(A=Vt rows(d), B=P cols(q)) ----
    __builtin_amdgcn_s_setprio(1);
#pragma unroll
    for (int ks = 0; ks < 4; ++ks) {
      const int pce = ks * 2 + h;
      bf16x8 av0 = *(const bf16x8*)((const char*)Vt[cur] + l31 * 128 + ((pce ^ (l31 >> 3)) * 16));
      bf16x8 av1 = *(const bf16x8*)((const char*)Vt[cur] + (32 + l31) * 128 + ((pce ^ (4 + (l31 >> 3))) * 16));
      ctx0 = __builtin_amdgcn_mfma_f32_32x32x16_bf16(av0, paf[ks], ctx0, 0, 0, 0);
      ctx1 = __builtin_amdgcn_mfma_f32_32x32x16_bf16(av1, paf[ks], ctx1, 0, 0, 0);
    }
    __builtin_amdgcn_s_setprio(0);

    __syncthreads();   // drains vmcnt (K[t+1] landed) + publishes Vt[nxt]
  }

  // ---- epilogue: O[q][d] = ctx^T / l ; d = (r&3)+8*(r>>2)+4h+32f ----
  const float inv = 1.0f / l;
  const long orow = row0 + w * 32 + l31;
#pragma unroll
  for (int f = 0; f < 2; ++f)
#pragma unroll
    for (int tq = 0; tq < 4; ++tq) {
      bf16x4 o;
#pragma unroll
      for (int e = 0; e < 4; ++e) {
        const float v = (f ? ctx1[tq * 4 + e] : ctx0[tq * 4 + e]) * inv;
        o[e] = (__bf16)v;
      }
      const int col = colQ + f * 32 + tq * 8 + h * 4;
      *(bf16x4*)&Og[orow * E + col] = o;
    }
}

// ---------------------------------------------------------------------------
extern "C" void kernel_launch(void* const* d_in, const int* in_sizes, int n_in,
                              void* d_out, int out_size, void* d_ws, size_t ws_size,
                              hipStream_t stream) {
  const float* x     = (const float*)d_in[0];
  const float* ln1g  = (const float*)d_in[1];
  const float* ln1b  = (const float*)d_in[2];
  const float* ln2g  = (const float*)d_in[3];
  const float* ln2b  = (const float*)d_in[4];
  const float* wq    = (const float*)d_in[5];
  const float* bq    = (const float*)d_in[6];
  const float* wk    = (const float*)d_in[7];
  const float* bk    = (const float*)d_in[8];
  const float* wv    = (const float*)d_in[9];
  const float* bv    = (const float*)d_in[10];
  const float* wo    = (const float*)d_in[11];
  const float* bo    = (const float*)d_in[12];
  const float* w1    = (const float*)d_in[13];
  const float* b1    = (const float*)d_in[14];
  const float* w2    = (const float*)d_in[15];
  const float* b2    = (const float*)d_in[16];
  float* out = (float*)d_out;

  char* ws = (char*)d_ws;
  const size_t MB = 1024 * 1024;
  __bf16* Wqkv = (__bf16*)(ws + 0 * MB);    // [3072][1024] bf16, 6MB (q|k|v rows)
  __bf16* Wot  = (__bf16*)(ws + 6 * MB);    // [1024][1024] 2MB
  __bf16* W1t  = (__bf16*)(ws + 8 * MB);    // [4096][1024] 8MB
  __bf16* W2t  = (__bf16*)(ws + 16 * MB);   // [1024][4096] 8MB
  __bf16* h    = (__bf16*)(ws + 24 * MB);   // [8192][1024] 16MB
  __bf16* qkv  = (__bf16*)(ws + 40 * MB);   // [8192][3072] 48MB
  __bf16* ctx  = (__bf16*)(ws + 88 * MB);   // [8192][1024] 16MB (total 104MB)
  __bf16* ff1  = (__bf16*)(ws + 40 * MB);   // [8192][4096] 64MB, aliases qkv (dead)

  const dim3 blk(256);
  const dim3 blk512(512);
  const size_t GLDS256 = 131072;   // BM=256: 2*(32KB A) + 2*(32KB B)
  const size_t GLDS128 = 98304;    // BM=128: 2*(16KB A) + 2*(32KB B)

  // weights -> bf16 transposed [N][K]; q/k/v stacked into Wqkv
  wconv_kernel<<<dim3(E / 32, E / 32), blk, 0, stream>>>(wq, Wqkv, E, E);
  wconv_kernel<<<dim3(E / 32, E / 32), blk, 0, stream>>>(wk, Wqkv + 1024 * 1024, E, E);
  wconv_kernel<<<dim3(E / 32, E / 32), blk, 0, stream>>>(wv, Wqkv + 2048 * 1024, E, E);
  wconv_kernel<<<dim3(E / 32, E / 32), blk, 0, stream>>>(wo, Wot, E, E);
  wconv_kernel<<<dim3(HID / 32, E / 32), blk, 0, stream>>>(w1, W1t, E, HID);
  wconv_kernel<<<dim3(E / 32, HID / 32), blk, 0, stream>>>(w2, W2t, HID, E);

  // LN1
  ln_kernel<<<TOK, blk, 0, stream>>>(x, ln1g, ln1b, h);

  // fused QKV projection: [8192][3072]   grid 12x32 = 384 blocks
  gemm256_kernel<256, false, false, true, 3><<<dim3(3072 / 256, TOK / 256), blk512, GLDS256, stream>>>(
      h, Wqkv, bq, bk, bv, nullptr, qkv, TOK, 3072, E);

  // attention: 8 q-blocks of 128 rows x 128 (b,h)
  attn_kernel<<<dim3(8, 128), blk, 0, stream>>>(qkv, ctx);

  // O projection + residual(x) -> d_out (fp32)   grid 4x64 = 256 blocks
  gemm256_kernel<128, false, true, false, 1><<<dim3(E / 256, TOK / 128), blk512, GLDS128, stream>>>(
      ctx, Wot, bo, nullptr, nullptr, x, out, TOK, E, E);

  // LN2 on d_out
  ln_kernel<<<TOK, blk, 0, stream>>>(out, ln2g, ln2b, h);

  // FF1 with ReLU -> ff1 (bf16)   grid 16x32 = 512 blocks
  gemm256_kernel<256, true, false, true, 1><<<dim3(HID / 256, TOK / 256), blk512, GLDS256, stream>>>(
      h, W1t, b1, nullptr, nullptr, nullptr, ff1, TOK, HID, E);

  // FF2 + residual(d_out) -> d_out (in-place, element-wise safe)   grid 4x64 = 256
  gemm256_kernel<128, false, true, false, 1><<<dim3(E / 256, TOK / 128), blk512, GLDS128, stream>>>(
      ff1, W2t, b2, nullptr, nullptr, out, out, TOK, E, HID);
}